// Round 6
// baseline (780.725 us; speedup 1.0000x reference)
//
#include <hip/hip_runtime.h>
#include <hip/hip_bf16.h>

typedef __attribute__((ext_vector_type(8))) short bf16x8;   // 8 bf16 (conv)
typedef __attribute__((ext_vector_type(4))) float f32x4;
typedef __attribute__((ext_vector_type(8))) _Float16 f16x8; // MFMA f16 A/B frag
typedef __attribute__((ext_vector_type(16))) float f32x16;  // 32x32 MFMA C/D
typedef __hip_bfloat16 bf16;
typedef unsigned short u16;

#define NB 8
#define NE 256
#define NN 4096
#define SD 64

__device__ __forceinline__ u16 f2b_bits(float x) {
  bf16 h = __float2bfloat16(x);
  return *reinterpret_cast<u16*>(&h);
}
__device__ __forceinline__ f32x16 z16() {
  f32x16 v;
#pragma unroll
  for (int i = 0; i < 16; ++i) v[i] = 0.f;
  return v;
}
__device__ __forceinline__ void gload_lds16(const void* g, void* l) {
  __builtin_amdgcn_global_load_lds((const __attribute__((address_space(1))) void*)g,
                                   (__attribute__((address_space(3))) void*)l, 16, 0, 0);
}

// lane-half swap: a' = {a_lo, b_lo}, b' = {a_hi, b_hi} (T12)
#if __has_builtin(__builtin_amdgcn_permlane32_swap)
typedef int i32x2 __attribute__((ext_vector_type(2)));
__device__ __forceinline__ void plswap(int& a, int& b) {
  i32x2 r = __builtin_amdgcn_permlane32_swap(a, b, false, false);
  a = r[0]; b = r[1];
}
#else
__device__ __forceinline__ void plswap(int& a, int& b) {
  int xa = __shfl_xor(a, 32), xb = __shfl_xor(b, 32);
  int hi = (int)((threadIdx.x & 63) >> 5);
  int na = hi ? xb : a;
  int nb = hi ? b : xa;
  a = na; b = nb;
}
#endif

// ---------------- split f32 -> bf16 hi/lo (conv inputs) ----------------
__global__ __launch_bounds__(256) void k_split(const float* __restrict__ x,
                                               u16* __restrict__ hi, u16* __restrict__ lo, int n4) {
  int i = blockIdx.x * 256 + threadIdx.x;
  if (i >= n4) return;
  float4 v = reinterpret_cast<const float4*>(x)[i];
  float f[4] = {v.x, v.y, v.z, v.w};
  u16 hh[4], ll[4];
#pragma unroll
  for (int j = 0; j < 4; ++j) {
    bf16 hb = __float2bfloat16(f[j]);
    float hf = __bfloat162float(hb);
    hh[j] = *reinterpret_cast<u16*>(&hb);
    ll[j] = f2b_bits(f[j] - hf);
  }
  reinterpret_cast<ushort4*>(hi)[i] = make_ushort4(hh[0], hh[1], hh[2], hh[3]);
  reinterpret_cast<ushort4*>(lo)[i] = make_ushort4(ll[0], ll[1], ll[2], ll[3]);
}

// ------- split + transpose conv weights: w[t][ei][eo] -> whT[t][eo][ei] -------
__global__ __launch_bounds__(256) void k_wsplit(const float* __restrict__ w,
                                                u16* __restrict__ whT, u16* __restrict__ wlT) {
  int i = blockIdx.x * 256 + threadIdx.x;
  int t = i >> 16;
  int r = i & 65535;
  int ei = r >> 8, eo = r & 255;
  float x = w[i];
  bf16 hb = __float2bfloat16(x);
  float hf = __bfloat162float(hb);
  int o = (t << 16) + (eo << 8) + ei;
  whT[o] = *reinterpret_cast<u16*>(&hb);
  wlT[o] = f2b_bits(x - hf);
}

// ---------------- conv 3x3 implicit GEMM, split-bf16; epilogue -> f16 ----------------
__global__ __launch_bounds__(256) void k_conv(const u16* __restrict__ inh, const u16* __restrict__ inl,
                                              const u16* __restrict__ whT, const u16* __restrict__ wlT,
                                              const float* __restrict__ bias,
                                              u16* __restrict__ x1h) {
  __shared__ u16 Ah[128][72], Al[128][72];
  __shared__ u16 Bh[128][72], Bl[128][72];
  int b = blockIdx.x >> 6;
  int rem = blockIdx.x & 63;
  int mt = rem >> 1, et = rem & 1;
  int h0 = mt << 1;
  int tid = threadIdx.x;
  int wid = tid >> 6, lane = tid & 63;
  int wr = wid >> 1, wc = wid & 1;
  int r = lane & 15, g = lane >> 4;
  f32x4 acc[4][4];
#pragma unroll
  for (int i = 0; i < 4; ++i)
#pragma unroll
    for (int j = 0; j < 4; ++j) acc[i][j] = (f32x4){0.f, 0.f, 0.f, 0.f};
  const long ibase = (long)b * NN * NE;

#pragma unroll 1
  for (int t = 0; t < 9; ++t) {
    int dy = t / 3 - 1, dx = t % 3 - 1;
#pragma unroll 1
    for (int kc = 0; kc < 4; ++kc) {
      __syncthreads();
      for (int c = tid; c < 1024; c += 256) {
        int pix = c >> 3, c8 = c & 7;
        int ww = pix & 63, hh = h0 + (pix >> 6);
        int sh = hh + dy, sw = ww + dx;
        float4 vh = make_float4(0.f, 0.f, 0.f, 0.f), vl = vh;
        if ((unsigned)sh < 64u && (unsigned)sw < 64u) {
          long off = ibase + ((long)sh * 64 + sw) * NE + kc * 64 + c8 * 8;
          vh = *reinterpret_cast<const float4*>(inh + off);
          vl = *reinterpret_cast<const float4*>(inl + off);
        }
        *reinterpret_cast<float4*>(&Ah[pix][c8 * 8]) = vh;
        *reinterpret_cast<float4*>(&Al[pix][c8 * 8]) = vl;
      }
      for (int c = tid; c < 1024; c += 256) {
        int eo = c >> 3, c8 = c & 7;
        long off = ((long)t << 16) + (et * 128 + eo) * 256 + kc * 64 + c8 * 8;
        *reinterpret_cast<float4*>(&Bh[eo][c8 * 8]) = *reinterpret_cast<const float4*>(whT + off);
        *reinterpret_cast<float4*>(&Bl[eo][c8 * 8]) = *reinterpret_cast<const float4*>(wlT + off);
      }
      __syncthreads();
#pragma unroll
      for (int ks = 0; ks < 2; ++ks) {
        int c8 = ks * 4 + g;
        bf16x8 ah[4], al[4], bh[4], bl[4];
#pragma unroll
        for (int mi = 0; mi < 4; ++mi) {
          int row = wr * 64 + mi * 16 + r;
          ah[mi] = *reinterpret_cast<const bf16x8*>(&Ah[row][c8 * 8]);
          al[mi] = *reinterpret_cast<const bf16x8*>(&Al[row][c8 * 8]);
        }
#pragma unroll
        for (int ni = 0; ni < 4; ++ni) {
          int col = wc * 64 + ni * 16 + r;
          bh[ni] = *reinterpret_cast<const bf16x8*>(&Bh[col][c8 * 8]);
          bl[ni] = *reinterpret_cast<const bf16x8*>(&Bl[col][c8 * 8]);
        }
#pragma unroll
        for (int mi = 0; mi < 4; ++mi)
#pragma unroll
          for (int ni = 0; ni < 4; ++ni) {
            acc[mi][ni] = __builtin_amdgcn_mfma_f32_16x16x32_bf16(ah[mi], bh[ni], acc[mi][ni], 0, 0, 0);
            acc[mi][ni] = __builtin_amdgcn_mfma_f32_16x16x32_bf16(ah[mi], bl[ni], acc[mi][ni], 0, 0, 0);
            acc[mi][ni] = __builtin_amdgcn_mfma_f32_16x16x32_bf16(al[mi], bh[ni], acc[mi][ni], 0, 0, 0);
          }
      }
    }
  }
#pragma unroll
  for (int mi = 0; mi < 4; ++mi)
#pragma unroll
    for (int ni = 0; ni < 4; ++ni) {
      int eo = et * 128 + wc * 64 + ni * 16 + r;
      float bz = bias[eo];
#pragma unroll
      for (int i = 0; i < 4; ++i) {
        int pix = mt * 128 + wr * 64 + mi * 16 + g * 4 + i;
        float v = acc[mi][ni][i] + bz;
        long o = ibase + (long)pix * NE + eo;
        x1h[o] = __builtin_bit_cast(u16, (_Float16)v);
      }
    }
}

// ---------------- transpose x1h[b][m][e] -> x1T[b][e][m] ----------------
__global__ __launch_bounds__(256) void k_trans(const u16* __restrict__ x1h, u16* __restrict__ x1T) {
  __shared__ u16 T[64][72];
  int bid = blockIdx.x;
  int b = bid >> 8, rem = bid & 255;
  int mt = rem >> 2, et = rem & 3;
  int tid = threadIdx.x;
  for (int c = tid; c < 512; c += 256) {
    int rr = c >> 3, c8 = c & 7;
    *reinterpret_cast<float4*>(&T[rr][c8 * 8]) =
        *reinterpret_cast<const float4*>(x1h + ((long)b * NN + mt * 64 + rr) * NE + et * 64 + c8 * 8);
  }
  __syncthreads();
  for (int c = tid; c < 512; c += 256) {
    int er = c >> 3, m8 = c & 7;
    union { u16 u[8]; float4 v; } p;
#pragma unroll
    for (int j = 0; j < 8; ++j) p.u[j] = T[m8 * 8 + j][er];
    *reinterpret_cast<float4*>(x1T + ((long)b * NE + et * 64 + er) * NN + mt * 64 + m8 * 8) = p.v;
  }
}

// ---------------- fused flash attention, f16, 32x32 MFMA ----------------
// block 512 = 8 waves; waves (qg, qg+4) co-own 32 q-rows (qg = wid&3), split KV by
// tile parity (KVBLK=32, 128 tiles, 64 per wave) with independent (m,l,O);
// merged at the end through LDS. Grid 256 (8b x 32mt, XCD-swizzled).
// __launch_bounds__(512,1): CUDA semantics (min 1 block/CU) -> 2 waves/SIMD @ 256 VGPR.
// K swz: row 512B, byte ^ ((r&7)<<4). V swz: row 64B, row-pair-swap via bit6
// (phys = e<<6 ^ ((e&4)<<4)) + byte ^ ((e&3)<<4) -> 8 distinct bank slots per 8 rows.
__device__ __forceinline__ void stage_pair(const u16* __restrict__ x1h16, const u16* __restrict__ x1T,
                                           char* LDS, int bufoff, long bN, long vtb,
                                           int pair, int wid, int lane) {
  int kvb = pair * 64;
#pragma unroll
  for (int i = 0; i < 8; ++i) {
    int c = wid * 8 + i;                        // 64 chunks of 1KB
    char* dst = LDS + bufoff + c * 1024;        // HW adds lane*16
    int region = c >> 4, cc = c & 15;
    if ((region & 1) == 0) {                    // K: chunk = 2 rows of 512B
      int r = cc * 2 + (lane >> 5);
      int colb = ((lane & 31) << 4) ^ ((r & 7) << 4);
      int kvr = kvb + ((region >> 1) << 5) + r;
      const u16* src = x1h16 + ((bN + kvr) << 8) + (colb >> 1);
      gload_lds16(src, dst);
    } else {                                    // V: chunk = 16 phys rows of 64B
      int rp = cc * 16 + (lane >> 2);           // physical row within 256
      int e = rp ^ ((rp >> 2) & 1);             // involutive row-pair swap
      int colb = ((lane & 3) << 4) ^ ((e & 3) << 4);
      int kv0 = kvb + ((region >> 1) << 5);
      const u16* src = x1T + vtb + ((long)e << 12) + kv0 + (colb >> 1);
      gload_lds16(src, dst);
    }
  }
}

__global__ __launch_bounds__(512, 1) void k_flash(const u16* __restrict__ x1h16,
                                                  const u16* __restrict__ x1T,
                                                  const float* __restrict__ inp,
                                                  float* __restrict__ out) {
  extern __shared__ char LDS[];
  int phys = blockIdx.x;
  int logical = (phys & 7) * 32 + (phys >> 3);  // XCD k <-> batch k (K/V L2-resident)
  int b = logical >> 5, mt = logical & 31;
  int tid = threadIdx.x, wid = tid >> 6, lane = tid & 63;
  int r31 = lane & 31, hi = lane >> 5;
  int qg = wid & 3, par = wid >> 2;
  const long bN = (long)b << 12;
  const long vtb = (long)b << 20;

  // Q (f16) in regs: B-frag of S^T=mfma(K,Q): col=lane&31=qrow, k=hi*8+j
  const long qrow = bN + mt * 128 + qg * 32 + r31;
  f16x8 qh[16];
#pragma unroll
  for (int ks = 0; ks < 16; ++ks)
    qh[ks] = *reinterpret_cast<const f16x8*>(x1h16 + (qrow << 8) + ks * 16 + hi * 8);

  f32x16 o8[8];
#pragma unroll
  for (int nf = 0; nf < 8; ++nf) o8[nf] = z16();
  float mrow = -1.0e30f, lrow = 0.f;

  stage_pair(x1h16, x1T, LDS, 0, bN, vtb, 0, wid, lane);

#pragma unroll 1
  for (int it = 0; it < 64; ++it) {
    int cb = (it & 1) * 65536;
    if (it < 63) {
      stage_pair(x1h16, x1T, LDS, 65536 - cb, bN, vtb, it + 1, wid, lane);
      asm volatile("s_waitcnt vmcnt(8)" ::: "memory");   // current pair's 8 done; next 8 in flight
    } else {
      asm volatile("s_waitcnt vmcnt(0)" ::: "memory");
    }
    __builtin_amdgcn_s_barrier();
    __builtin_amdgcn_sched_barrier(0);

    const char* TB = LDS + cb + par * 32768;    // my parity's K tile
    const char* VB = TB + 16384;                // my parity's V tile

    // ---- S^T = K.Q (32 kv x 32 q) ----
    f32x16 st = z16();
    int swzk = (r31 & 7) << 4;
    int krow = r31 << 9;
    __builtin_amdgcn_s_setprio(1);
#pragma unroll
    for (int ks = 0; ks < 16; ++ks) {
      int cby = (ks * 32 + hi * 16) ^ swzk;
      f16x8 k0 = *reinterpret_cast<const f16x8*>(TB + krow + cby);
      st = __builtin_amdgcn_mfma_f32_32x32x16_f16(k0, qh[ks], st, 0, 0, 0);
    }
    __builtin_amdgcn_s_setprio(0);

    // ---- online softmax (qrow = lane&31; kv = (m&3)+8*(m>>2)+4*hi) ----
    float tmax = st[0];
#pragma unroll
    for (int m = 1; m < 16; ++m) tmax = fmaxf(tmax, st[m]);
    tmax = fmaxf(tmax, __shfl_xor(tmax, 32));
    if (!__all(tmax <= mrow + 8.0f)) {          // defer-max (T13)
      float mnew = fmaxf(mrow, tmax);
      float alpha = __expf(mrow - mnew);
      lrow *= alpha;
      float ar[16];
#pragma unroll
      for (int m = 0; m < 16; ++m) ar[m] = __shfl(alpha, (m & 3) + 8 * (m >> 2) + 4 * hi);
#pragma unroll
      for (int nf = 0; nf < 8; ++nf)
#pragma unroll
        for (int m = 0; m < 16; ++m) o8[nf][m] *= ar[m];
      mrow = mnew;
    }
    float psum = 0.f;
#pragma unroll
    for (int m = 0; m < 16; ++m) { float p = __expf(st[m] - mrow); st[m] = p; psum += p; }
    psum += __shfl_xor(psum, 32);
    lrow += psum;

    // ---- P -> f16, re-fragment via permlane32_swap: 2 A-frags (kv chunks of 16) ----
    int Wd[8];
#pragma unroll
    for (int m = 0; m < 8; ++m) {
      unsigned l0 = __builtin_bit_cast(u16, (_Float16)st[2 * m]);
      unsigned h0 = __builtin_bit_cast(u16, (_Float16)st[2 * m + 1]);
      Wd[m] = (int)(l0 | (h0 << 16));
    }
    plswap(Wd[0], Wd[2]); plswap(Wd[1], Wd[3]);
    plswap(Wd[4], Wd[6]); plswap(Wd[5], Wd[7]);
    union PU { int w[4]; f16x8 v; };
    PU pa[2];
#pragma unroll
    for (int c = 0; c < 2; ++c) {
      pa[c].w[0] = Wd[c * 4 + 0]; pa[c].w[1] = Wd[c * 4 + 1];
      pa[c].w[2] = Wd[c * 4 + 2]; pa[c].w[3] = Wd[c * 4 + 3];
    }

    // ---- O += P.V ----
    __builtin_amdgcn_s_setprio(1);
#pragma unroll
    for (int nf = 0; nf < 8; ++nf) {
      int e = nf * 32 + r31;
      const char* vrow = VB + ((e << 6) ^ ((e & 4) << 4));   // bit6 row-pair swap
      int swzv = (e & 3) << 4;
#pragma unroll
      for (int c = 0; c < 2; ++c) {
        f16x8 v = *reinterpret_cast<const f16x8*>(vrow + ((c * 32 + hi * 16) ^ swzv));
        o8[nf] = __builtin_amdgcn_mfma_f32_32x32x16_f16(pa[c].v, v, o8[nf], 0, 0, 0);
      }
    }
    __builtin_amdgcn_s_setprio(0);
    __builtin_amdgcn_s_barrier();
  }

  // ---- merge parity pairs through LDS, then epilogue ----
  float* L = (float*)LDS;
  const int ML = 32768;                          // float index of m/l exchange region
  __syncthreads();
  if (par == 1) {
    if (hi == 0) {
      L[ML + qg * 64 + r31] = mrow;
      L[ML + qg * 64 + 32 + r31] = lrow;
    }
#pragma unroll
    for (int nf = 0; nf < 8; ++nf)
#pragma unroll
      for (int m = 0; m < 16; ++m) {
        int qr = (m & 3) + 8 * (m >> 2) + 4 * hi;
        L[qg * 8192 + qr * 256 + nf * 32 + r31] = o8[nf][m];
      }
  }
  __syncthreads();
  if (par == 0) {
    float m1 = L[ML + qg * 64 + r31];
    float l1 = L[ML + qg * 64 + 32 + r31];
    float ms = fmaxf(mrow, m1);
    float f0 = __expf(mrow - ms), f1 = __expf(m1 - ms);
    float lst = f0 * lrow + f1 * l1;
    float linv = 1.0f / (16.0f * lst);
    float f0s[16], f1s[16], lin[16];
#pragma unroll
    for (int m = 0; m < 16; ++m) {
      int qr = (m & 3) + 8 * (m >> 2) + 4 * hi;
      f0s[m] = __shfl(f0, qr);
      f1s[m] = __shfl(f1, qr);
      lin[m] = __shfl(linv, qr);
    }
    const long ob = (bN + mt * 128 + qg * 32) << 8;
#pragma unroll
    for (int nf = 0; nf < 8; ++nf)
#pragma unroll
      for (int m = 0; m < 16; ++m) {
        int qr = (m & 3) + 8 * (m >> 2) + 4 * hi;
        float o1 = L[qg * 8192 + qr * 256 + nf * 32 + r31];
        long off = ob + ((long)qr << 8) + nf * 32 + r31;
        out[off] = (f0s[m] * o8[nf][m] + f1s[m] * o1) * lin[m] * inp[off];
      }
  }
}

// ---------------- host ----------------
extern "C" void kernel_launch(void* const* d_in, const int* in_sizes, int n_in,
                              void* d_out, int out_size, void* d_ws, size_t ws_size,
                              hipStream_t stream) {
  const float* inp   = (const float*)d_in[0];
  const float* convw = (const float*)d_in[1];
  const float* convb = (const float*)d_in[2];
  float* out = (float*)d_out;
  char* ws = (char*)d_ws;

  u16* x1h   = (u16*)(ws);                 // f16
  u16* x1T   = (u16*)(ws + 16777216L);     // f16, transposed
  u16* in_hi = (u16*)(ws + 33554432L);     // bf16 (conv input split)
  u16* in_lo = (u16*)(ws + 50331648L);
  u16* whT   = (u16*)(ws + 67108864L);
  u16* wlT   = (u16*)(ws + 67108864L + 1179648L);

  (void)hipFuncSetAttribute((const void*)k_flash,
                            hipFuncAttributeMaxDynamicSharedMemorySize, 132096);

  k_split<<<8192, 256, 0, stream>>>(inp, in_hi, in_lo, 2097152);
  k_wsplit<<<2304, 256, 0, stream>>>(convw, whT, wlT);
  k_conv<<<512, 256, 0, stream>>>(in_hi, in_lo, whT, wlT, convb, x1h);
  k_trans<<<2048, 256, 0, stream>>>(x1h, x1T);
  k_flash<<<256, 512, 132096, stream>>>(x1h, x1T, inp, out);
}

// Round 7
// 534.135 us; speedup vs baseline: 1.4617x; 1.4617x over previous
//
#include <hip/hip_runtime.h>
#include <hip/hip_bf16.h>

typedef __attribute__((ext_vector_type(8))) short bf16x8;   // 8 bf16 (conv)
typedef __attribute__((ext_vector_type(4))) float f32x4;
typedef __attribute__((ext_vector_type(8))) _Float16 f16x8; // MFMA f16 A/B frag
typedef __attribute__((ext_vector_type(16))) float f32x16;  // 32x32 MFMA C/D
typedef __hip_bfloat16 bf16;
typedef unsigned short u16;

#define NB 8
#define NE 256
#define NN 4096
#define SD 64

__device__ __forceinline__ u16 f2b_bits(float x) {
  bf16 h = __float2bfloat16(x);
  return *reinterpret_cast<u16*>(&h);
}
__device__ __forceinline__ f32x16 z16() {
  f32x16 v;
#pragma unroll
  for (int i = 0; i < 16; ++i) v[i] = 0.f;
  return v;
}
__device__ __forceinline__ void gload_lds16(const void* g, void* l) {
  __builtin_amdgcn_global_load_lds((const __attribute__((address_space(1))) void*)g,
                                   (__attribute__((address_space(3))) void*)l, 16, 0, 0);
}

// lane-half swap: a' = {a_lo, b_lo}, b' = {a_hi, b_hi} (T12)
#if __has_builtin(__builtin_amdgcn_permlane32_swap)
typedef int i32x2 __attribute__((ext_vector_type(2)));
__device__ __forceinline__ void plswap(int& a, int& b) {
  i32x2 r = __builtin_amdgcn_permlane32_swap(a, b, false, false);
  a = r[0]; b = r[1];
}
#else
__device__ __forceinline__ void plswap(int& a, int& b) {
  int xa = __shfl_xor(a, 32), xb = __shfl_xor(b, 32);
  int hi = (int)((threadIdx.x & 63) >> 5);
  int na = hi ? xb : a;
  int nb = hi ? b : xa;
  a = na; b = nb;
}
#endif

// ---------------- split f32 -> bf16 hi/lo (conv inputs) ----------------
__global__ __launch_bounds__(256) void k_split(const float* __restrict__ x,
                                               u16* __restrict__ hi, u16* __restrict__ lo, int n4) {
  int i = blockIdx.x * 256 + threadIdx.x;
  if (i >= n4) return;
  float4 v = reinterpret_cast<const float4*>(x)[i];
  float f[4] = {v.x, v.y, v.z, v.w};
  u16 hh[4], ll[4];
#pragma unroll
  for (int j = 0; j < 4; ++j) {
    bf16 hb = __float2bfloat16(f[j]);
    float hf = __bfloat162float(hb);
    hh[j] = *reinterpret_cast<u16*>(&hb);
    ll[j] = f2b_bits(f[j] - hf);
  }
  reinterpret_cast<ushort4*>(hi)[i] = make_ushort4(hh[0], hh[1], hh[2], hh[3]);
  reinterpret_cast<ushort4*>(lo)[i] = make_ushort4(ll[0], ll[1], ll[2], ll[3]);
}

// ------- split + transpose conv weights: w[t][ei][eo] -> whT[t][eo][ei] -------
__global__ __launch_bounds__(256) void k_wsplit(const float* __restrict__ w,
                                                u16* __restrict__ whT, u16* __restrict__ wlT) {
  int i = blockIdx.x * 256 + threadIdx.x;
  int t = i >> 16;
  int r = i & 65535;
  int ei = r >> 8, eo = r & 255;
  float x = w[i];
  bf16 hb = __float2bfloat16(x);
  float hf = __bfloat162float(hb);
  int o = (t << 16) + (eo << 8) + ei;
  whT[o] = *reinterpret_cast<u16*>(&hb);
  wlT[o] = f2b_bits(x - hf);
}

// ---------------- conv 3x3 implicit GEMM, split-bf16; epilogue -> f16 ----------------
__global__ __launch_bounds__(256) void k_conv(const u16* __restrict__ inh, const u16* __restrict__ inl,
                                              const u16* __restrict__ whT, const u16* __restrict__ wlT,
                                              const float* __restrict__ bias,
                                              u16* __restrict__ x1h) {
  __shared__ u16 Ah[128][72], Al[128][72];
  __shared__ u16 Bh[128][72], Bl[128][72];
  int b = blockIdx.x >> 6;
  int rem = blockIdx.x & 63;
  int mt = rem >> 1, et = rem & 1;
  int h0 = mt << 1;
  int tid = threadIdx.x;
  int wid = tid >> 6, lane = tid & 63;
  int wr = wid >> 1, wc = wid & 1;
  int r = lane & 15, g = lane >> 4;
  f32x4 acc[4][4];
#pragma unroll
  for (int i = 0; i < 4; ++i)
#pragma unroll
    for (int j = 0; j < 4; ++j) acc[i][j] = (f32x4){0.f, 0.f, 0.f, 0.f};
  const long ibase = (long)b * NN * NE;

#pragma unroll 1
  for (int t = 0; t < 9; ++t) {
    int dy = t / 3 - 1, dx = t % 3 - 1;
#pragma unroll 1
    for (int kc = 0; kc < 4; ++kc) {
      __syncthreads();
      for (int c = tid; c < 1024; c += 256) {
        int pix = c >> 3, c8 = c & 7;
        int ww = pix & 63, hh = h0 + (pix >> 6);
        int sh = hh + dy, sw = ww + dx;
        float4 vh = make_float4(0.f, 0.f, 0.f, 0.f), vl = vh;
        if ((unsigned)sh < 64u && (unsigned)sw < 64u) {
          long off = ibase + ((long)sh * 64 + sw) * NE + kc * 64 + c8 * 8;
          vh = *reinterpret_cast<const float4*>(inh + off);
          vl = *reinterpret_cast<const float4*>(inl + off);
        }
        *reinterpret_cast<float4*>(&Ah[pix][c8 * 8]) = vh;
        *reinterpret_cast<float4*>(&Al[pix][c8 * 8]) = vl;
      }
      for (int c = tid; c < 1024; c += 256) {
        int eo = c >> 3, c8 = c & 7;
        long off = ((long)t << 16) + (et * 128 + eo) * 256 + kc * 64 + c8 * 8;
        *reinterpret_cast<float4*>(&Bh[eo][c8 * 8]) = *reinterpret_cast<const float4*>(whT + off);
        *reinterpret_cast<float4*>(&Bl[eo][c8 * 8]) = *reinterpret_cast<const float4*>(wlT + off);
      }
      __syncthreads();
#pragma unroll
      for (int ks = 0; ks < 2; ++ks) {
        int c8 = ks * 4 + g;
        bf16x8 ah[4], al[4], bh[4], bl[4];
#pragma unroll
        for (int mi = 0; mi < 4; ++mi) {
          int row = wr * 64 + mi * 16 + r;
          ah[mi] = *reinterpret_cast<const bf16x8*>(&Ah[row][c8 * 8]);
          al[mi] = *reinterpret_cast<const bf16x8*>(&Al[row][c8 * 8]);
        }
#pragma unroll
        for (int ni = 0; ni < 4; ++ni) {
          int col = wc * 64 + ni * 16 + r;
          bh[ni] = *reinterpret_cast<const bf16x8*>(&Bh[col][c8 * 8]);
          bl[ni] = *reinterpret_cast<const bf16x8*>(&Bl[col][c8 * 8]);
        }
#pragma unroll
        for (int mi = 0; mi < 4; ++mi)
#pragma unroll
          for (int ni = 0; ni < 4; ++ni) {
            acc[mi][ni] = __builtin_amdgcn_mfma_f32_16x16x32_bf16(ah[mi], bh[ni], acc[mi][ni], 0, 0, 0);
            acc[mi][ni] = __builtin_amdgcn_mfma_f32_16x16x32_bf16(ah[mi], bl[ni], acc[mi][ni], 0, 0, 0);
            acc[mi][ni] = __builtin_amdgcn_mfma_f32_16x16x32_bf16(al[mi], bh[ni], acc[mi][ni], 0, 0, 0);
          }
      }
    }
  }
#pragma unroll
  for (int mi = 0; mi < 4; ++mi)
#pragma unroll
    for (int ni = 0; ni < 4; ++ni) {
      int eo = et * 128 + wc * 64 + ni * 16 + r;
      float bz = bias[eo];
#pragma unroll
      for (int i = 0; i < 4; ++i) {
        int pix = mt * 128 + wr * 64 + mi * 16 + g * 4 + i;
        float v = acc[mi][ni][i] + bz;
        long o = ibase + (long)pix * NE + eo;
        x1h[o] = __builtin_bit_cast(u16, (_Float16)v);
      }
    }
}

// ---------------- transpose x1h[b][m][e] -> x1T[b][e][m] ----------------
__global__ __launch_bounds__(256) void k_trans(const u16* __restrict__ x1h, u16* __restrict__ x1T) {
  __shared__ u16 T[64][72];
  int bid = blockIdx.x;
  int b = bid >> 8, rem = bid & 255;
  int mt = rem >> 2, et = rem & 3;
  int tid = threadIdx.x;
  for (int c = tid; c < 512; c += 256) {
    int rr = c >> 3, c8 = c & 7;
    *reinterpret_cast<float4*>(&T[rr][c8 * 8]) =
        *reinterpret_cast<const float4*>(x1h + ((long)b * NN + mt * 64 + rr) * NE + et * 64 + c8 * 8);
  }
  __syncthreads();
  for (int c = tid; c < 512; c += 256) {
    int er = c >> 3, m8 = c & 7;
    union { u16 u[8]; float4 v; } p;
#pragma unroll
    for (int j = 0; j < 8; ++j) p.u[j] = T[m8 * 8 + j][er];
    *reinterpret_cast<float4*>(x1T + ((long)b * NE + et * 64 + er) * NN + mt * 64 + m8 * 8) = p.v;
  }
}

// ---------------- fused flash attention (partial-KV), f16, 32x32 MFMA ----------------
// grid 512 = 8b x 32mt x 2 KV-halves (XCD-swizzled: phys&7 = batch = XCD).
// block 256 = 4 waves, wave owns 32 q-rows over its 2048-key half.
// KVBLK=32 double-buffered: buf 32KB = K[32][512B] + V[256 phys rows][64B]; 2 bufs = 64KB
// -> 2 blocks/CU = 2 waves/SIMD @ 256 VGPR (256-thread blocks proven spill-free, R4).
// Partial (unnormalized O, m, l) written to ws; k_merge combines halves exactly.
// K swz: byte ^ ((r&7)<<4) in 512B rows. V swz: row-pair swap bit6 (phys = e<<6 ^ ((e&4)<<4))
// + byte ^ ((e&3)<<4). Sources pre-swizzled; gload_lds dest linear (rule 21).
__device__ __forceinline__ void stage_tile2(const u16* __restrict__ x1h16, const u16* __restrict__ x1T,
                                            char* LDS, int bufoff, long bN, long vtb,
                                            int kv0, int wid, int lane) {
#pragma unroll
  for (int i = 0; i < 8; ++i) {
    int c = wid * 8 + i;                        // 32 chunks of 1KB
    char* dst = LDS + bufoff + c * 1024;        // HW adds lane*16
    if (c < 16) {                               // K: chunk = 2 rows of 512B
      int r = c * 2 + (lane >> 5);
      int colb = ((lane & 31) << 4) ^ ((r & 7) << 4);
      const u16* src = x1h16 + ((bN + kv0 + r) << 8) + (colb >> 1);
      gload_lds16(src, dst);
    } else {                                    // V: chunk = 16 phys rows of 64B
      int rp = (c - 16) * 16 + (lane >> 2);
      int e = rp ^ ((rp >> 2) & 1);             // involutive row-pair swap
      int colb = ((lane & 3) << 4) ^ ((e & 3) << 4);
      const u16* src = x1T + vtb + ((long)e << 12) + kv0 + (colb >> 1);
      gload_lds16(src, dst);
    }
  }
}

__global__ __launch_bounds__(256, 1) void k_flash2(const u16* __restrict__ x1h16,
                                                   const u16* __restrict__ x1T,
                                                   float* __restrict__ Opart,
                                                   float* __restrict__ mlbuf) {
  extern __shared__ char LDS[];
  int phys = blockIdx.x;
  int b = phys & 7;                             // batch == XCD
  int half = (phys >> 3) & 1;
  int mt = (phys >> 4) & 31;
  int tid = threadIdx.x, wid = tid >> 6, lane = tid & 63;
  int r31 = lane & 31, hi = lane >> 5;
  const long bN = (long)b << 12;
  const long vtb = (long)b << 20;
  const int kvbase = half << 11;                // 0 or 2048

  // Q (f16) in regs: B-frag of S^T=mfma(K,Q): col=lane&31=qrow, k=hi*8+j
  const long qrow = bN + mt * 128 + wid * 32 + r31;
  f16x8 qh[16];
#pragma unroll
  for (int ks = 0; ks < 16; ++ks)
    qh[ks] = *reinterpret_cast<const f16x8*>(x1h16 + (qrow << 8) + ks * 16 + hi * 8);

  f32x16 o8[8];
#pragma unroll
  for (int nf = 0; nf < 8; ++nf) o8[nf] = z16();
  float mrow = -1.0e30f, lrow = 0.f;

  stage_tile2(x1h16, x1T, LDS, 0, bN, vtb, kvbase, wid, lane);

#pragma unroll 1
  for (int it = 0; it < 64; ++it) {
    int cb = (it & 1) << 15;                    // 32KB buffers
    if (it < 63) {
      stage_tile2(x1h16, x1T, LDS, 32768 - cb, bN, vtb, kvbase + (it + 1) * 32, wid, lane);
      asm volatile("s_waitcnt vmcnt(8)" ::: "memory");   // current tile's 8 done; next 8 in flight
    } else {
      asm volatile("s_waitcnt vmcnt(0)" ::: "memory");
    }
    __builtin_amdgcn_s_barrier();
    __builtin_amdgcn_sched_barrier(0);

    const char* TB = LDS + cb;                  // K tile
    const char* VB = TB + 16384;                // V tile

    // ---- S^T = K.Q (32 kv x 32 q) ----
    f32x16 st = z16();
    int swzk = (r31 & 7) << 4;
    int krow = r31 << 9;
    __builtin_amdgcn_s_setprio(1);
#pragma unroll
    for (int ks = 0; ks < 16; ++ks) {
      int cby = (ks * 32 + hi * 16) ^ swzk;
      f16x8 k0 = *reinterpret_cast<const f16x8*>(TB + krow + cby);
      st = __builtin_amdgcn_mfma_f32_32x32x16_f16(k0, qh[ks], st, 0, 0, 0);
    }
    __builtin_amdgcn_s_setprio(0);

    // ---- online softmax (qrow = lane&31; kv = (m&3)+8*(m>>2)+4*hi) ----
    float tmax = st[0];
#pragma unroll
    for (int m = 1; m < 16; ++m) tmax = fmaxf(tmax, st[m]);
    tmax = fmaxf(tmax, __shfl_xor(tmax, 32));
    if (!__all(tmax <= mrow + 8.0f)) {          // defer-max (T13)
      float mnew = fmaxf(mrow, tmax);
      float alpha = __expf(mrow - mnew);
      lrow *= alpha;
      float ar[16];
#pragma unroll
      for (int m = 0; m < 16; ++m) ar[m] = __shfl(alpha, (m & 3) + 8 * (m >> 2) + 4 * hi);
#pragma unroll
      for (int nf = 0; nf < 8; ++nf)
#pragma unroll
        for (int m = 0; m < 16; ++m) o8[nf][m] *= ar[m];
      mrow = mnew;
    }
    float psum = 0.f;
#pragma unroll
    for (int m = 0; m < 16; ++m) { float p = __expf(st[m] - mrow); st[m] = p; psum += p; }
    psum += __shfl_xor(psum, 32);
    lrow += psum;

    // ---- P -> f16, re-fragment via permlane32_swap: 2 A-frags (kv chunks of 16) ----
    int Wd[8];
#pragma unroll
    for (int m = 0; m < 8; ++m) {
      unsigned l0 = __builtin_bit_cast(u16, (_Float16)st[2 * m]);
      unsigned h0 = __builtin_bit_cast(u16, (_Float16)st[2 * m + 1]);
      Wd[m] = (int)(l0 | (h0 << 16));
    }
    plswap(Wd[0], Wd[2]); plswap(Wd[1], Wd[3]);
    plswap(Wd[4], Wd[6]); plswap(Wd[5], Wd[7]);
    union PU { int w[4]; f16x8 v; };
    PU pa[2];
#pragma unroll
    for (int c = 0; c < 2; ++c) {
      pa[c].w[0] = Wd[c * 4 + 0]; pa[c].w[1] = Wd[c * 4 + 1];
      pa[c].w[2] = Wd[c * 4 + 2]; pa[c].w[3] = Wd[c * 4 + 3];
    }

    // ---- O += P.V ----
    __builtin_amdgcn_s_setprio(1);
#pragma unroll
    for (int nf = 0; nf < 8; ++nf) {
      int e = nf * 32 + r31;
      const char* vrow = VB + ((e << 6) ^ ((e & 4) << 4));   // bit6 row-pair swap
      int swzv = (e & 3) << 4;
#pragma unroll
      for (int c = 0; c < 2; ++c) {
        f16x8 v = *reinterpret_cast<const f16x8*>(vrow + ((c * 32 + hi * 16) ^ swzv));
        o8[nf] = __builtin_amdgcn_mfma_f32_32x32x16_f16(pa[c].v, v, o8[nf], 0, 0, 0);
      }
    }
    __builtin_amdgcn_s_setprio(0);
    __builtin_amdgcn_s_barrier();
  }

  // ---- write partials: unnormalized O, and (m,l) per q-row ----
  const long grow0 = bN + mt * 128 + wid * 32;  // global q-row base of this wave
  float* Oh = Opart + (long)half * 8388608;
  if (hi == 0) {
    mlbuf[half * 65536 + grow0 + r31] = mrow;
    mlbuf[half * 65536 + 32768 + grow0 + r31] = lrow;
  }
#pragma unroll
  for (int nf = 0; nf < 8; ++nf)
#pragma unroll
    for (int m = 0; m < 16; ++m) {
      int qr = (m & 3) + 8 * (m >> 2) + 4 * hi;
      Oh[((grow0 + qr) << 8) + nf * 32 + r31] = o8[nf][m];
    }
}

// ---------------- merge two KV-halves: exact exp-rescale combine, /16 * inp ----------------
__global__ __launch_bounds__(256) void k_merge(const float* __restrict__ O0, const float* __restrict__ O1,
                                               const float* __restrict__ mlbuf,
                                               const float* __restrict__ inp, float* __restrict__ out) {
  int g = blockIdx.x * 256 + threadIdx.x;       // float4 index, 2097152 total
  long off = (long)g << 2;
  int row = (int)(off >> 8);
  float m0 = mlbuf[row], l0 = mlbuf[32768 + row];
  float m1 = mlbuf[65536 + row], l1 = mlbuf[98304 + row];
  float M = fmaxf(m0, m1);
  float f0 = __expf(m0 - M), f1 = __expf(m1 - M);
  float s = 1.0f / (16.0f * (f0 * l0 + f1 * l1));
  float4 a = reinterpret_cast<const float4*>(O0)[g];
  float4 b = reinterpret_cast<const float4*>(O1)[g];
  float4 x = reinterpret_cast<const float4*>(inp)[g];
  float4 o;
  o.x = (f0 * a.x + f1 * b.x) * s * x.x;
  o.y = (f0 * a.y + f1 * b.y) * s * x.y;
  o.z = (f0 * a.z + f1 * b.z) * s * x.z;
  o.w = (f0 * a.w + f1 * b.w) * s * x.w;
  reinterpret_cast<float4*>(out)[g] = o;
}

// ---------------- host ----------------
// ws layout (bytes):
//   [0,   16M)  x1h f16
//   [16M, 32M)  x1T f16
//   [32M, 64M)  O0 f32   (during conv phase: in_hi@32M, in_lo@48M — dead after conv)
//   [64M, 96M)  O1 f32   (during conv phase: whT@64M, wlT@65.2M — dead after conv)
//   [96M, 96.5M) mlbuf (m0,l0,m1,l1 per q-row)
extern "C" void kernel_launch(void* const* d_in, const int* in_sizes, int n_in,
                              void* d_out, int out_size, void* d_ws, size_t ws_size,
                              hipStream_t stream) {
  const float* inp   = (const float*)d_in[0];
  const float* convw = (const float*)d_in[1];
  const float* convb = (const float*)d_in[2];
  float* out = (float*)d_out;
  char* ws = (char*)d_ws;

  u16* x1h   = (u16*)(ws);                 // f16
  u16* x1T   = (u16*)(ws + 16777216L);     // f16, transposed
  float* O0  = (float*)(ws + 33554432L);
  float* O1  = (float*)(ws + 67108864L);
  float* ml  = (float*)(ws + 100663296L);
  u16* in_hi = (u16*)(ws + 33554432L);     // conv temps, die before k_flash2
  u16* in_lo = (u16*)(ws + 50331648L);
  u16* whT   = (u16*)(ws + 67108864L);
  u16* wlT   = (u16*)(ws + 67108864L + 1179648L);

  (void)hipFuncSetAttribute((const void*)k_flash2,
                            hipFuncAttributeMaxDynamicSharedMemorySize, 65536);

  k_split<<<8192, 256, 0, stream>>>(inp, in_hi, in_lo, 2097152);
  k_wsplit<<<2304, 256, 0, stream>>>(convw, whT, wlT);
  k_conv<<<512, 256, 0, stream>>>(in_hi, in_lo, whT, wlT, convb, x1h);
  k_trans<<<2048, 256, 0, stream>>>(x1h, x1T);
  k_flash2<<<512, 256, 65536, stream>>>(x1h, x1T, O0, ml);
  k_merge<<<8192, 256, 0, stream>>>(O0, O1, ml, inp, out);
}

// Round 8
// 499.307 us; speedup vs baseline: 1.5636x; 1.0698x over previous
//
#include <hip/hip_runtime.h>
#include <hip/hip_bf16.h>

typedef __attribute__((ext_vector_type(8))) short bf16x8;   // 8 bf16 (conv)
typedef __attribute__((ext_vector_type(4))) float f32x4;
typedef __attribute__((ext_vector_type(8))) _Float16 f16x8; // MFMA f16 A/B frag
typedef __attribute__((ext_vector_type(16))) float f32x16;  // 32x32 MFMA C/D
typedef __hip_bfloat16 bf16;
typedef unsigned short u16;

#define NB 8
#define NE 256
#define NN 4096
#define SD 64

__device__ __forceinline__ u16 f2b_bits(float x) {
  bf16 h = __float2bfloat16(x);
  return *reinterpret_cast<u16*>(&h);
}
__device__ __forceinline__ f32x16 z16() {
  f32x16 v;
#pragma unroll
  for (int i = 0; i < 16; ++i) v[i] = 0.f;
  return v;
}
__device__ __forceinline__ void gload_lds16(const void* g, void* l) {
  __builtin_amdgcn_global_load_lds((const __attribute__((address_space(1))) void*)g,
                                   (__attribute__((address_space(3))) void*)l, 16, 0, 0);
}

// lane-half swap: a' = {a_lo, b_lo}, b' = {a_hi, b_hi} (T12)
#if __has_builtin(__builtin_amdgcn_permlane32_swap)
typedef int i32x2 __attribute__((ext_vector_type(2)));
__device__ __forceinline__ void plswap(int& a, int& b) {
  i32x2 r = __builtin_amdgcn_permlane32_swap(a, b, false, false);
  a = r[0]; b = r[1];
}
#else
__device__ __forceinline__ void plswap(int& a, int& b) {
  int xa = __shfl_xor(a, 32), xb = __shfl_xor(b, 32);
  int hi = (int)((threadIdx.x & 63) >> 5);
  int na = hi ? xb : a;
  int nb = hi ? b : xa;
  a = na; b = nb;
}
#endif

// ---------------- split f32 -> bf16 hi/lo (conv inputs) ----------------
__global__ __launch_bounds__(256) void k_split(const float* __restrict__ x,
                                               u16* __restrict__ hi, u16* __restrict__ lo, int n4) {
  int i = blockIdx.x * 256 + threadIdx.x;
  if (i >= n4) return;
  float4 v = reinterpret_cast<const float4*>(x)[i];
  float f[4] = {v.x, v.y, v.z, v.w};
  u16 hh[4], ll[4];
#pragma unroll
  for (int j = 0; j < 4; ++j) {
    bf16 hb = __float2bfloat16(f[j]);
    float hf = __bfloat162float(hb);
    hh[j] = *reinterpret_cast<u16*>(&hb);
    ll[j] = f2b_bits(f[j] - hf);
  }
  reinterpret_cast<ushort4*>(hi)[i] = make_ushort4(hh[0], hh[1], hh[2], hh[3]);
  reinterpret_cast<ushort4*>(lo)[i] = make_ushort4(ll[0], ll[1], ll[2], ll[3]);
}

// ------- split + transpose conv weights: w[t][ei][eo] -> whT[t][eo][ei] -------
__global__ __launch_bounds__(256) void k_wsplit(const float* __restrict__ w,
                                                u16* __restrict__ whT, u16* __restrict__ wlT) {
  int i = blockIdx.x * 256 + threadIdx.x;
  int t = i >> 16;
  int r = i & 65535;
  int ei = r >> 8, eo = r & 255;
  float x = w[i];
  bf16 hb = __float2bfloat16(x);
  float hf = __bfloat162float(hb);
  int o = (t << 16) + (eo << 8) + ei;
  whT[o] = *reinterpret_cast<u16*>(&hb);
  wlT[o] = f2b_bits(x - hf);
}

// ---------------- conv 3x3 implicit GEMM, split-bf16; epilogue -> f16 ----------------
__global__ __launch_bounds__(256) void k_conv(const u16* __restrict__ inh, const u16* __restrict__ inl,
                                              const u16* __restrict__ whT, const u16* __restrict__ wlT,
                                              const float* __restrict__ bias,
                                              u16* __restrict__ x1h) {
  __shared__ u16 Ah[128][72], Al[128][72];
  __shared__ u16 Bh[128][72], Bl[128][72];
  int b = blockIdx.x >> 6;
  int rem = blockIdx.x & 63;
  int mt = rem >> 1, et = rem & 1;
  int h0 = mt << 1;
  int tid = threadIdx.x;
  int wid = tid >> 6, lane = tid & 63;
  int wr = wid >> 1, wc = wid & 1;
  int r = lane & 15, g = lane >> 4;
  f32x4 acc[4][4];
#pragma unroll
  for (int i = 0; i < 4; ++i)
#pragma unroll
    for (int j = 0; j < 4; ++j) acc[i][j] = (f32x4){0.f, 0.f, 0.f, 0.f};
  const long ibase = (long)b * NN * NE;

#pragma unroll 1
  for (int t = 0; t < 9; ++t) {
    int dy = t / 3 - 1, dx = t % 3 - 1;
#pragma unroll 1
    for (int kc = 0; kc < 4; ++kc) {
      __syncthreads();
      for (int c = tid; c < 1024; c += 256) {
        int pix = c >> 3, c8 = c & 7;
        int ww = pix & 63, hh = h0 + (pix >> 6);
        int sh = hh + dy, sw = ww + dx;
        float4 vh = make_float4(0.f, 0.f, 0.f, 0.f), vl = vh;
        if ((unsigned)sh < 64u && (unsigned)sw < 64u) {
          long off = ibase + ((long)sh * 64 + sw) * NE + kc * 64 + c8 * 8;
          vh = *reinterpret_cast<const float4*>(inh + off);
          vl = *reinterpret_cast<const float4*>(inl + off);
        }
        *reinterpret_cast<float4*>(&Ah[pix][c8 * 8]) = vh;
        *reinterpret_cast<float4*>(&Al[pix][c8 * 8]) = vl;
      }
      for (int c = tid; c < 1024; c += 256) {
        int eo = c >> 3, c8 = c & 7;
        long off = ((long)t << 16) + (et * 128 + eo) * 256 + kc * 64 + c8 * 8;
        *reinterpret_cast<float4*>(&Bh[eo][c8 * 8]) = *reinterpret_cast<const float4*>(whT + off);
        *reinterpret_cast<float4*>(&Bl[eo][c8 * 8]) = *reinterpret_cast<const float4*>(wlT + off);
      }
      __syncthreads();
#pragma unroll
      for (int ks = 0; ks < 2; ++ks) {
        int c8 = ks * 4 + g;
        bf16x8 ah[4], al[4], bh[4], bl[4];
#pragma unroll
        for (int mi = 0; mi < 4; ++mi) {
          int row = wr * 64 + mi * 16 + r;
          ah[mi] = *reinterpret_cast<const bf16x8*>(&Ah[row][c8 * 8]);
          al[mi] = *reinterpret_cast<const bf16x8*>(&Al[row][c8 * 8]);
        }
#pragma unroll
        for (int ni = 0; ni < 4; ++ni) {
          int col = wc * 64 + ni * 16 + r;
          bh[ni] = *reinterpret_cast<const bf16x8*>(&Bh[col][c8 * 8]);
          bl[ni] = *reinterpret_cast<const bf16x8*>(&Bl[col][c8 * 8]);
        }
#pragma unroll
        for (int mi = 0; mi < 4; ++mi)
#pragma unroll
          for (int ni = 0; ni < 4; ++ni) {
            acc[mi][ni] = __builtin_amdgcn_mfma_f32_16x16x32_bf16(ah[mi], bh[ni], acc[mi][ni], 0, 0, 0);
            acc[mi][ni] = __builtin_amdgcn_mfma_f32_16x16x32_bf16(ah[mi], bl[ni], acc[mi][ni], 0, 0, 0);
            acc[mi][ni] = __builtin_amdgcn_mfma_f32_16x16x32_bf16(al[mi], bh[ni], acc[mi][ni], 0, 0, 0);
          }
      }
    }
  }
#pragma unroll
  for (int mi = 0; mi < 4; ++mi)
#pragma unroll
    for (int ni = 0; ni < 4; ++ni) {
      int eo = et * 128 + wc * 64 + ni * 16 + r;
      float bz = bias[eo];
#pragma unroll
      for (int i = 0; i < 4; ++i) {
        int pix = mt * 128 + wr * 64 + mi * 16 + g * 4 + i;
        float v = acc[mi][ni][i] + bz;
        long o = ibase + (long)pix * NE + eo;
        x1h[o] = __builtin_bit_cast(u16, (_Float16)v);
      }
    }
}

// ---------------- transpose x1h[b][m][e] -> x1T[b][e][m] ----------------
__global__ __launch_bounds__(256) void k_trans(const u16* __restrict__ x1h, u16* __restrict__ x1T) {
  __shared__ u16 T[64][72];
  int bid = blockIdx.x;
  int b = bid >> 8, rem = bid & 255;
  int mt = rem >> 2, et = rem & 3;
  int tid = threadIdx.x;
  for (int c = tid; c < 512; c += 256) {
    int rr = c >> 3, c8 = c & 7;
    *reinterpret_cast<float4*>(&T[rr][c8 * 8]) =
        *reinterpret_cast<const float4*>(x1h + ((long)b * NN + mt * 64 + rr) * NE + et * 64 + c8 * 8);
  }
  __syncthreads();
  for (int c = tid; c < 512; c += 256) {
    int er = c >> 3, m8 = c & 7;
    union { u16 u[8]; float4 v; } p;
#pragma unroll
    for (int j = 0; j < 8; ++j) p.u[j] = T[m8 * 8 + j][er];
    *reinterpret_cast<float4*>(x1T + ((long)b * NE + et * 64 + er) * NN + mt * 64 + m8 * 8) = p.v;
  }
}

// ---------------- fused flash attention (partial-KV), f16, 32x32 MFMA ----------------
// grid 512 = 8b x 32mt x 2 KV-halves (phys&7 = batch = XCD). block 256 = 4 waves,
// wave owns 32 q-rows over its 2048-key half. STATIC 48KB LDS: K dbuf 2x16KB @0/@16K,
// V single 16KB @32K. Iter: vmcnt(0)[K ready] barrier; QK; issue V(it)+K(it+1);
// softmax; vmcnt(4)[V ready] barrier; PV. V single-buffer safe: the K-ready barrier
// follows PV(it-1) in program order, so all waves are done reading V before restage.
// K swz: byte ^ ((r&15)<<4) in 512B rows (2-way = free). V swz: bit6 row-pair swap
// + ((e&3)<<4) in 64B rows. Sources pre-swizzled; gload_lds dest linear (rule 21).
__device__ __forceinline__ void stage_K(const u16* __restrict__ x1h16, char* dstb,
                                        long bN, int kv0, int wid, int lane) {
#pragma unroll
  for (int i = 0; i < 4; ++i) {
    int c = wid * 4 + i;                        // 16 chunks of 1KB (2 rows each)
    int r = c * 2 + (lane >> 5);
    int colb = ((lane & 31) << 4) ^ ((r & 15) << 4);
    const u16* src = x1h16 + ((bN + kv0 + r) << 8) + (colb >> 1);
    gload_lds16(src, dstb + c * 1024);          // HW adds lane*16
  }
}
__device__ __forceinline__ void stage_V(const u16* __restrict__ x1T, char* dstb,
                                        long vtb, int kv0, int wid, int lane) {
#pragma unroll
  for (int i = 0; i < 4; ++i) {
    int c = wid * 4 + i;                        // 16 chunks of 1KB (16 phys rows of 64B)
    int rp = c * 16 + (lane >> 2);
    int e = rp ^ ((rp >> 2) & 1);               // involutive row-pair swap
    int colb = ((lane & 3) << 4) ^ ((e & 3) << 4);
    const u16* src = x1T + vtb + ((long)e << 12) + kv0 + (colb >> 1);
    gload_lds16(src, dstb + c * 1024);
  }
}

__global__ __launch_bounds__(256, 1) void k_flash2(const u16* __restrict__ x1h16,
                                                   const u16* __restrict__ x1T,
                                                   float* __restrict__ Opart,
                                                   float* __restrict__ mlbuf) {
  __shared__ char LDS[49152];
  int phys = blockIdx.x;
  int b = phys & 7;                             // batch == XCD
  int half = (phys >> 3) & 1;
  int mt = (phys >> 4) & 31;
  int tid = threadIdx.x, wid = tid >> 6, lane = tid & 63;
  int r31 = lane & 31, hi = lane >> 5;
  const long bN = (long)b << 12;
  const long vtb = (long)b << 20;
  const int kvbase = half << 11;                // 0 or 2048

  // Q (f16) in regs: B-frag of S^T=mfma(K,Q): col=lane&31=qrow, k=hi*8+j
  const long qrow = bN + mt * 128 + wid * 32 + r31;
  f16x8 qh[16];
#pragma unroll
  for (int ks = 0; ks < 16; ++ks)
    qh[ks] = *reinterpret_cast<const f16x8*>(x1h16 + (qrow << 8) + ks * 16 + hi * 8);

  f32x16 o8[8];
#pragma unroll
  for (int nf = 0; nf < 8; ++nf) o8[nf] = z16();
  float mrow = -1.0e30f, lrow = 0.f;

  stage_K(x1h16, LDS, bN, kvbase, wid, lane);   // K(0) -> buf0

#pragma unroll 1
  for (int it = 0; it < 64; ++it) {
    const char* KB = LDS + (it & 1) * 16384;
    const char* VB = LDS + 32768;

    asm volatile("s_waitcnt vmcnt(0)" ::: "memory");   // own K(it) landed (issued last iter)
    __builtin_amdgcn_s_barrier();                      // all waves: K(it) ready, PV(it-1) done
    __builtin_amdgcn_sched_barrier(0);

    // ---- S^T = K.Q (32 kv x 32 q) ----
    f32x16 st = z16();
    int swzk = (r31 & 15) << 4;
    int krow = r31 << 9;
    __builtin_amdgcn_s_setprio(1);
#pragma unroll
    for (int ks = 0; ks < 16; ++ks) {
      int cby = (ks * 32 + hi * 16) ^ swzk;
      f16x8 k0 = *reinterpret_cast<const f16x8*>(KB + krow + cby);
      st = __builtin_amdgcn_mfma_f32_32x32x16_f16(k0, qh[ks], st, 0, 0, 0);
    }
    __builtin_amdgcn_s_setprio(0);

    // ---- issue next stages: V(it) into single V buf; K(it+1) into other K buf ----
    stage_V(x1T, (char*)VB, vtb, kvbase + it * 32, wid, lane);
    if (it < 63)
      stage_K(x1h16, LDS + ((it + 1) & 1) * 16384, bN, kvbase + (it + 1) * 32, wid, lane);

    // ---- online softmax (qrow = lane&31; kv = (m&3)+8*(m>>2)+4*hi) ----
    float tmax = st[0];
#pragma unroll
    for (int m = 1; m < 16; ++m) tmax = fmaxf(tmax, st[m]);
    tmax = fmaxf(tmax, __shfl_xor(tmax, 32));
    if (!__all(tmax <= mrow + 8.0f)) {          // defer-max (T13)
      float mnew = fmaxf(mrow, tmax);
      float alpha = __expf(mrow - mnew);
      lrow *= alpha;
      float ar[16];
#pragma unroll
      for (int m = 0; m < 16; ++m) ar[m] = __shfl(alpha, (m & 3) + 8 * (m >> 2) + 4 * hi);
#pragma unroll
      for (int nf = 0; nf < 8; ++nf)
#pragma unroll
        for (int m = 0; m < 16; ++m) o8[nf][m] *= ar[m];
      mrow = mnew;
    }
    float psum = 0.f;
#pragma unroll
    for (int m = 0; m < 16; ++m) { float p = __expf(st[m] - mrow); st[m] = p; psum += p; }
    psum += __shfl_xor(psum, 32);
    lrow += psum;

    // ---- P -> f16, re-fragment via permlane32_swap: 2 A-frags (kv chunks of 16) ----
    int Wd[8];
#pragma unroll
    for (int m = 0; m < 8; ++m) {
      unsigned l0 = __builtin_bit_cast(u16, (_Float16)st[2 * m]);
      unsigned h0 = __builtin_bit_cast(u16, (_Float16)st[2 * m + 1]);
      Wd[m] = (int)(l0 | (h0 << 16));
    }
    plswap(Wd[0], Wd[2]); plswap(Wd[1], Wd[3]);
    plswap(Wd[4], Wd[6]); plswap(Wd[5], Wd[7]);
    union PU { int w[4]; f16x8 v; };
    PU pa[2];
#pragma unroll
    for (int c = 0; c < 2; ++c) {
      pa[c].w[0] = Wd[c * 4 + 0]; pa[c].w[1] = Wd[c * 4 + 1];
      pa[c].w[2] = Wd[c * 4 + 2]; pa[c].w[3] = Wd[c * 4 + 3];
    }

    // ---- wait V(it), sync, then O += P.V ----
    if (it < 63) {
      asm volatile("s_waitcnt vmcnt(4)" ::: "memory");  // V(it) done; K(it+1) still in flight
    } else {
      asm volatile("s_waitcnt vmcnt(0)" ::: "memory");
    }
    __builtin_amdgcn_s_barrier();
    __builtin_amdgcn_sched_barrier(0);

    __builtin_amdgcn_s_setprio(1);
#pragma unroll
    for (int nf = 0; nf < 8; ++nf) {
      int e = nf * 32 + r31;
      const char* vrow = VB + ((e << 6) ^ ((e & 4) << 4));   // bit6 row-pair swap
      int swzv = (e & 3) << 4;
#pragma unroll
      for (int c = 0; c < 2; ++c) {
        f16x8 v = *reinterpret_cast<const f16x8*>(vrow + ((c * 32 + hi * 16) ^ swzv));
        o8[nf] = __builtin_amdgcn_mfma_f32_32x32x16_f16(pa[c].v, v, o8[nf], 0, 0, 0);
      }
    }
    __builtin_amdgcn_s_setprio(0);
  }

  // ---- write partials: unnormalized O, and (m,l) per q-row ----
  const long grow0 = bN + mt * 128 + wid * 32;  // global q-row base of this wave
  float* Oh = Opart + (long)half * 8388608;
  if (hi == 0) {
    mlbuf[half * 65536 + grow0 + r31] = mrow;
    mlbuf[half * 65536 + 32768 + grow0 + r31] = lrow;
  }
#pragma unroll
  for (int nf = 0; nf < 8; ++nf)
#pragma unroll
    for (int m = 0; m < 16; ++m) {
      int qr = (m & 3) + 8 * (m >> 2) + 4 * hi;
      Oh[((grow0 + qr) << 8) + nf * 32 + r31] = o8[nf][m];
    }
}

// ---------------- merge two KV-halves: exact exp-rescale combine, /16 * inp ----------------
__global__ __launch_bounds__(256) void k_merge(const float* __restrict__ O0, const float* __restrict__ O1,
                                               const float* __restrict__ mlbuf,
                                               const float* __restrict__ inp, float* __restrict__ out) {
  int g = blockIdx.x * 256 + threadIdx.x;       // float4 index, 2097152 total
  long off = (long)g << 2;
  int row = (int)(off >> 8);
  float m0 = mlbuf[row], l0 = mlbuf[32768 + row];
  float m1 = mlbuf[65536 + row], l1 = mlbuf[98304 + row];
  float M = fmaxf(m0, m1);
  float f0 = __expf(m0 - M), f1 = __expf(m1 - M);
  float s = 1.0f / (16.0f * (f0 * l0 + f1 * l1));
  float4 a = reinterpret_cast<const float4*>(O0)[g];
  float4 b = reinterpret_cast<const float4*>(O1)[g];
  float4 x = reinterpret_cast<const float4*>(inp)[g];
  float4 o;
  o.x = (f0 * a.x + f1 * b.x) * s * x.x;
  o.y = (f0 * a.y + f1 * b.y) * s * x.y;
  o.z = (f0 * a.z + f1 * b.z) * s * x.z;
  o.w = (f0 * a.w + f1 * b.w) * s * x.w;
  reinterpret_cast<float4*>(out)[g] = o;
}

// ---------------- host ----------------
// ws layout (bytes):
//   [0,   16M)  x1h f16
//   [16M, 32M)  x1T f16
//   [32M, 64M)  O0 f32   (during conv phase: in_hi@32M, in_lo@48M — dead after conv)
//   [64M, 96M)  O1 f32   (during conv phase: whT@64M, wlT@65.2M — dead after conv)
//   [96M, 96.5M) mlbuf (m0,l0,m1,l1 per q-row)
extern "C" void kernel_launch(void* const* d_in, const int* in_sizes, int n_in,
                              void* d_out, int out_size, void* d_ws, size_t ws_size,
                              hipStream_t stream) {
  const float* inp   = (const float*)d_in[0];
  const float* convw = (const float*)d_in[1];
  const float* convb = (const float*)d_in[2];
  float* out = (float*)d_out;
  char* ws = (char*)d_ws;

  u16* x1h   = (u16*)(ws);                 // f16
  u16* x1T   = (u16*)(ws + 16777216L);     // f16, transposed
  float* O0  = (float*)(ws + 33554432L);
  float* O1  = (float*)(ws + 67108864L);
  float* ml  = (float*)(ws + 100663296L);
  u16* in_hi = (u16*)(ws + 33554432L);     // conv temps, die before k_flash2
  u16* in_lo = (u16*)(ws + 50331648L);
  u16* whT   = (u16*)(ws + 67108864L);
  u16* wlT   = (u16*)(ws + 67108864L + 1179648L);

  k_split<<<8192, 256, 0, stream>>>(inp, in_hi, in_lo, 2097152);
  k_wsplit<<<2304, 256, 0, stream>>>(convw, whT, wlT);
  k_conv<<<512, 256, 0, stream>>>(in_hi, in_lo, whT, wlT, convb, x1h);
  k_trans<<<2048, 256, 0, stream>>>(x1h, x1T);
  k_flash2<<<512, 256, 0, stream>>>(x1h, x1T, O0, ml);
  k_merge<<<8192, 256, 0, stream>>>(O0, O1, ml, inp, out);
}

// Round 9
// 431.227 us; speedup vs baseline: 1.8105x; 1.1579x over previous
//
#include <hip/hip_runtime.h>
#include <hip/hip_bf16.h>

typedef __attribute__((ext_vector_type(8))) short bf16x8;   // 8 bf16 (conv)
typedef __attribute__((ext_vector_type(4))) float f32x4;
typedef __attribute__((ext_vector_type(8))) _Float16 f16x8; // MFMA f16 A/B frag
typedef __attribute__((ext_vector_type(16))) float f32x16;  // 32x32 MFMA C/D
typedef __hip_bfloat16 bf16;
typedef unsigned short u16;

#define NB 8
#define NE 256
#define NN 4096
#define SD 64

__device__ __forceinline__ u16 f2b_bits(float x) {
  bf16 h = __float2bfloat16(x);
  return *reinterpret_cast<u16*>(&h);
}
__device__ __forceinline__ f32x16 z16() {
  f32x16 v;
#pragma unroll
  for (int i = 0; i < 16; ++i) v[i] = 0.f;
  return v;
}
__device__ __forceinline__ void gload_lds16(const void* g, void* l) {
  __builtin_amdgcn_global_load_lds((const __attribute__((address_space(1))) void*)g,
                                   (__attribute__((address_space(3))) void*)l, 16, 0, 0);
}

// lane-half swap: a' = {a_lo, b_lo}, b' = {a_hi, b_hi} (T12)
#if __has_builtin(__builtin_amdgcn_permlane32_swap)
typedef int i32x2 __attribute__((ext_vector_type(2)));
__device__ __forceinline__ void plswap(int& a, int& b) {
  i32x2 r = __builtin_amdgcn_permlane32_swap(a, b, false, false);
  a = r[0]; b = r[1];
}
#else
__device__ __forceinline__ void plswap(int& a, int& b) {
  int xa = __shfl_xor(a, 32), xb = __shfl_xor(b, 32);
  int hi = (int)((threadIdx.x & 63) >> 5);
  int na = hi ? xb : a;
  int nb = hi ? b : xa;
  a = na; b = nb;
}
#endif

// ---------------- split f32 -> bf16 hi/lo (conv inputs) ----------------
__global__ __launch_bounds__(256) void k_split(const float* __restrict__ x,
                                               u16* __restrict__ hi, u16* __restrict__ lo, int n4) {
  int i = blockIdx.x * 256 + threadIdx.x;
  if (i >= n4) return;
  float4 v = reinterpret_cast<const float4*>(x)[i];
  float f[4] = {v.x, v.y, v.z, v.w};
  u16 hh[4], ll[4];
#pragma unroll
  for (int j = 0; j < 4; ++j) {
    bf16 hb = __float2bfloat16(f[j]);
    float hf = __bfloat162float(hb);
    hh[j] = *reinterpret_cast<u16*>(&hb);
    ll[j] = f2b_bits(f[j] - hf);
  }
  reinterpret_cast<ushort4*>(hi)[i] = make_ushort4(hh[0], hh[1], hh[2], hh[3]);
  reinterpret_cast<ushort4*>(lo)[i] = make_ushort4(ll[0], ll[1], ll[2], ll[3]);
}

// ------- split + transpose conv weights: w[t][ei][eo] -> whT[t][eo][ei] -------
__global__ __launch_bounds__(256) void k_wsplit(const float* __restrict__ w,
                                                u16* __restrict__ whT, u16* __restrict__ wlT) {
  int i = blockIdx.x * 256 + threadIdx.x;
  int t = i >> 16;
  int r = i & 65535;
  int ei = r >> 8, eo = r & 255;
  float x = w[i];
  bf16 hb = __float2bfloat16(x);
  float hf = __bfloat162float(hb);
  int o = (t << 16) + (eo << 8) + ei;
  whT[o] = *reinterpret_cast<u16*>(&hb);
  wlT[o] = f2b_bits(x - hf);
}

// ---------------- conv 3x3 implicit GEMM, split-bf16; epilogue -> f16 ----------------
__global__ __launch_bounds__(256) void k_conv(const u16* __restrict__ inh, const u16* __restrict__ inl,
                                              const u16* __restrict__ whT, const u16* __restrict__ wlT,
                                              const float* __restrict__ bias,
                                              u16* __restrict__ x1h) {
  __shared__ u16 Ah[128][72], Al[128][72];
  __shared__ u16 Bh[128][72], Bl[128][72];
  int b = blockIdx.x >> 6;
  int rem = blockIdx.x & 63;
  int mt = rem >> 1, et = rem & 1;
  int h0 = mt << 1;
  int tid = threadIdx.x;
  int wid = tid >> 6, lane = tid & 63;
  int wr = wid >> 1, wc = wid & 1;
  int r = lane & 15, g = lane >> 4;
  f32x4 acc[4][4];
#pragma unroll
  for (int i = 0; i < 4; ++i)
#pragma unroll
    for (int j = 0; j < 4; ++j) acc[i][j] = (f32x4){0.f, 0.f, 0.f, 0.f};
  const long ibase = (long)b * NN * NE;

#pragma unroll 1
  for (int t = 0; t < 9; ++t) {
    int dy = t / 3 - 1, dx = t % 3 - 1;
#pragma unroll 1
    for (int kc = 0; kc < 4; ++kc) {
      __syncthreads();
      for (int c = tid; c < 1024; c += 256) {
        int pix = c >> 3, c8 = c & 7;
        int ww = pix & 63, hh = h0 + (pix >> 6);
        int sh = hh + dy, sw = ww + dx;
        float4 vh = make_float4(0.f, 0.f, 0.f, 0.f), vl = vh;
        if ((unsigned)sh < 64u && (unsigned)sw < 64u) {
          long off = ibase + ((long)sh * 64 + sw) * NE + kc * 64 + c8 * 8;
          vh = *reinterpret_cast<const float4*>(inh + off);
          vl = *reinterpret_cast<const float4*>(inl + off);
        }
        *reinterpret_cast<float4*>(&Ah[pix][c8 * 8]) = vh;
        *reinterpret_cast<float4*>(&Al[pix][c8 * 8]) = vl;
      }
      for (int c = tid; c < 1024; c += 256) {
        int eo = c >> 3, c8 = c & 7;
        long off = ((long)t << 16) + (et * 128 + eo) * 256 + kc * 64 + c8 * 8;
        *reinterpret_cast<float4*>(&Bh[eo][c8 * 8]) = *reinterpret_cast<const float4*>(whT + off);
        *reinterpret_cast<float4*>(&Bl[eo][c8 * 8]) = *reinterpret_cast<const float4*>(wlT + off);
      }
      __syncthreads();
#pragma unroll
      for (int ks = 0; ks < 2; ++ks) {
        int c8 = ks * 4 + g;
        bf16x8 ah[4], al[4], bh[4], bl[4];
#pragma unroll
        for (int mi = 0; mi < 4; ++mi) {
          int row = wr * 64 + mi * 16 + r;
          ah[mi] = *reinterpret_cast<const bf16x8*>(&Ah[row][c8 * 8]);
          al[mi] = *reinterpret_cast<const bf16x8*>(&Al[row][c8 * 8]);
        }
#pragma unroll
        for (int ni = 0; ni < 4; ++ni) {
          int col = wc * 64 + ni * 16 + r;
          bh[ni] = *reinterpret_cast<const bf16x8*>(&Bh[col][c8 * 8]);
          bl[ni] = *reinterpret_cast<const bf16x8*>(&Bl[col][c8 * 8]);
        }
#pragma unroll
        for (int mi = 0; mi < 4; ++mi)
#pragma unroll
          for (int ni = 0; ni < 4; ++ni) {
            acc[mi][ni] = __builtin_amdgcn_mfma_f32_16x16x32_bf16(ah[mi], bh[ni], acc[mi][ni], 0, 0, 0);
            acc[mi][ni] = __builtin_amdgcn_mfma_f32_16x16x32_bf16(ah[mi], bl[ni], acc[mi][ni], 0, 0, 0);
            acc[mi][ni] = __builtin_amdgcn_mfma_f32_16x16x32_bf16(al[mi], bh[ni], acc[mi][ni], 0, 0, 0);
          }
      }
    }
  }
#pragma unroll
  for (int mi = 0; mi < 4; ++mi)
#pragma unroll
    for (int ni = 0; ni < 4; ++ni) {
      int eo = et * 128 + wc * 64 + ni * 16 + r;
      float bz = bias[eo];
#pragma unroll
      for (int i = 0; i < 4; ++i) {
        int pix = mt * 128 + wr * 64 + mi * 16 + g * 4 + i;
        float v = acc[mi][ni][i] + bz;
        long o = ibase + (long)pix * NE + eo;
        x1h[o] = __builtin_bit_cast(u16, (_Float16)v);
      }
    }
}

// ---------------- transpose x1h[b][m][e] -> x1T[b][e][m] ----------------
__global__ __launch_bounds__(256) void k_trans(const u16* __restrict__ x1h, u16* __restrict__ x1T) {
  __shared__ u16 T[64][72];
  int bid = blockIdx.x;
  int b = bid >> 8, rem = bid & 255;
  int mt = rem >> 2, et = rem & 3;
  int tid = threadIdx.x;
  for (int c = tid; c < 512; c += 256) {
    int rr = c >> 3, c8 = c & 7;
    *reinterpret_cast<float4*>(&T[rr][c8 * 8]) =
        *reinterpret_cast<const float4*>(x1h + ((long)b * NN + mt * 64 + rr) * NE + et * 64 + c8 * 8);
  }
  __syncthreads();
  for (int c = tid; c < 512; c += 256) {
    int er = c >> 3, m8 = c & 7;
    union { u16 u[8]; float4 v; } p;
#pragma unroll
    for (int j = 0; j < 8; ++j) p.u[j] = T[m8 * 8 + j][er];
    *reinterpret_cast<float4*>(x1T + ((long)b * NE + et * 64 + er) * NN + mt * 64 + m8 * 8) = p.v;
  }
}

// ---------------- fused flash attention, f16, 32x32 MFMA, e-split waves ----------------
// grid 512 = 8b x 64 q-tiles of 64 rows (phys&7 = batch = XCD). block 256 = 4 waves:
// eh = wid&1 (output-dim half), qg = wid>>1 (q-group). Each wave: 32 q-rows x 128 dims.
// QK duplicated across the 2 e-half waves (MFMA x1.5 total) to halve accumulator state:
// o[4] = 64 regs -> total/wave ~190 <= 256 -> 2 blocks/CU (__launch_bounds__(256,2)).
// Full 4096-KV sweep per block (128 iters, KVBLK=32), writes final out (no merge pass).
// LDS 48KB static: K dbuf 2x16KB @0/@16K, V single 16KB @32K. Iter: vmcnt(0)[K ready]
// barrier; QK; issue V(it)+K(it+1); softmax; vmcnt(4)[V ready] barrier; PV.
// K swz: byte ^ ((r&15)<<4) in 512B rows. V swz: bit6 row-pair swap + ((e&3)<<4).
__device__ __forceinline__ void stage_K(const u16* __restrict__ x1h16, char* dstb,
                                        long bN, int kv0, int wid, int lane) {
#pragma unroll
  for (int i = 0; i < 4; ++i) {
    int c = wid * 4 + i;                        // 16 chunks of 1KB (2 rows each)
    int r = c * 2 + (lane >> 5);
    int colb = ((lane & 31) << 4) ^ ((r & 15) << 4);
    const u16* src = x1h16 + ((bN + kv0 + r) << 8) + (colb >> 1);
    gload_lds16(src, dstb + c * 1024);          // HW adds lane*16
  }
}
__device__ __forceinline__ void stage_V(const u16* __restrict__ x1T, char* dstb,
                                        long vtb, int kv0, int wid, int lane) {
#pragma unroll
  for (int i = 0; i < 4; ++i) {
    int c = wid * 4 + i;                        // 16 chunks of 1KB (16 phys rows of 64B)
    int rp = c * 16 + (lane >> 2);
    int e = rp ^ ((rp >> 2) & 1);               // involutive row-pair swap
    int colb = ((lane & 3) << 4) ^ ((e & 3) << 4);
    const u16* src = x1T + vtb + ((long)e << 12) + kv0 + (colb >> 1);
    gload_lds16(src, dstb + c * 1024);
  }
}

__global__ __launch_bounds__(256, 2) void k_flash3(const u16* __restrict__ x1h16,
                                                   const u16* __restrict__ x1T,
                                                   const float* __restrict__ inp,
                                                   float* __restrict__ out) {
  __shared__ char LDS[49152];
  int phys = blockIdx.x;
  int b = phys & 7;                             // batch == XCD
  int qt = phys >> 3;                           // q-tile of 64 rows (0..63)
  int tid = threadIdx.x, wid = tid >> 6, lane = tid & 63;
  int r31 = lane & 31, hi = lane >> 5;
  int eh = wid & 1, qg = wid >> 1;
  const long bN = (long)b << 12;
  const long vtb = (long)b << 20;

  // Q (f16) in regs: B-frag of S^T=mfma(K,Q): col=lane&31=qrow, k=hi*8+j
  const long qrow = bN + qt * 64 + qg * 32 + r31;
  f16x8 qh[16];
#pragma unroll
  for (int ks = 0; ks < 16; ++ks)
    qh[ks] = *reinterpret_cast<const f16x8*>(x1h16 + (qrow << 8) + ks * 16 + hi * 8);

  f32x16 o4[4];                                 // 128 output dims (eh half) = 64 regs
#pragma unroll
  for (int nf = 0; nf < 4; ++nf) o4[nf] = z16();
  float mrow = -1.0e30f, lrow = 0.f;

  stage_K(x1h16, LDS, bN, 0, wid, lane);        // K(0) -> buf0

#pragma unroll 1
  for (int it = 0; it < 128; ++it) {
    const char* KB = LDS + (it & 1) * 16384;
    const char* VB = LDS + 32768;

    asm volatile("s_waitcnt vmcnt(0)" ::: "memory");   // own K(it) landed (issued last iter)
    __builtin_amdgcn_s_barrier();                      // all waves: K(it) ready, PV(it-1) done
    __builtin_amdgcn_sched_barrier(0);

    // ---- S^T = K.Q (32 kv x 32 q) ----
    f32x16 st = z16();
    int swzk = (r31 & 15) << 4;
    int krow = r31 << 9;
    __builtin_amdgcn_s_setprio(1);
#pragma unroll
    for (int ks = 0; ks < 16; ++ks) {
      int cby = (ks * 32 + hi * 16) ^ swzk;
      f16x8 k0 = *reinterpret_cast<const f16x8*>(KB + krow + cby);
      st = __builtin_amdgcn_mfma_f32_32x32x16_f16(k0, qh[ks], st, 0, 0, 0);
    }
    __builtin_amdgcn_s_setprio(0);

    // ---- issue next stages: V(it) into single V buf; K(it+1) into other K buf ----
    stage_V(x1T, (char*)VB, vtb, it * 32, wid, lane);
    if (it < 127)
      stage_K(x1h16, LDS + ((it + 1) & 1) * 16384, bN, (it + 1) * 32, wid, lane);

    // ---- online softmax (qrow = lane&31; kv = (m&3)+8*(m>>2)+4*hi), tree reduces ----
    float t8[8];
#pragma unroll
    for (int m = 0; m < 8; ++m) t8[m] = fmaxf(st[m], st[m + 8]);
    float t4a = fmaxf(t8[0], t8[4]), t4b = fmaxf(t8[1], t8[5]);
    float t4c = fmaxf(t8[2], t8[6]), t4d = fmaxf(t8[3], t8[7]);
    float tmax = fmaxf(fmaxf(t4a, t4b), fmaxf(t4c, t4d));
    tmax = fmaxf(tmax, __shfl_xor(tmax, 32));
    if (!__all(tmax <= mrow + 8.0f)) {          // defer-max (T13)
      float mnew = fmaxf(mrow, tmax);
      float alpha = __expf(mrow - mnew);
      lrow *= alpha;
      float ar[16];
#pragma unroll
      for (int m = 0; m < 16; ++m) ar[m] = __shfl(alpha, (m & 3) + 8 * (m >> 2) + 4 * hi);
#pragma unroll
      for (int nf = 0; nf < 4; ++nf)
#pragma unroll
        for (int m = 0; m < 16; ++m) o4[nf][m] *= ar[m];
      mrow = mnew;
    }
#pragma unroll
    for (int m = 0; m < 16; ++m) st[m] = __expf(st[m] - mrow);
    float s8[8];
#pragma unroll
    for (int m = 0; m < 8; ++m) s8[m] = st[m] + st[m + 8];
    float s4a = s8[0] + s8[4], s4b = s8[1] + s8[5], s4c = s8[2] + s8[6], s4d = s8[3] + s8[7];
    float psum = (s4a + s4b) + (s4c + s4d);
    psum += __shfl_xor(psum, 32);
    lrow += psum;

    // ---- P -> f16, re-fragment via permlane32_swap: 2 A-frags (kv chunks of 16) ----
    int Wd[8];
#pragma unroll
    for (int m = 0; m < 8; ++m) {
      unsigned l0 = __builtin_bit_cast(u16, (_Float16)st[2 * m]);
      unsigned h0 = __builtin_bit_cast(u16, (_Float16)st[2 * m + 1]);
      Wd[m] = (int)(l0 | (h0 << 16));
    }
    plswap(Wd[0], Wd[2]); plswap(Wd[1], Wd[3]);
    plswap(Wd[4], Wd[6]); plswap(Wd[5], Wd[7]);
    union PU { int w[4]; f16x8 v; };
    PU pa[2];
#pragma unroll
    for (int c = 0; c < 2; ++c) {
      pa[c].w[0] = Wd[c * 4 + 0]; pa[c].w[1] = Wd[c * 4 + 1];
      pa[c].w[2] = Wd[c * 4 + 2]; pa[c].w[3] = Wd[c * 4 + 3];
    }

    // ---- wait V(it), sync, then O += P.V over this wave's e-half ----
    if (it < 127) {
      asm volatile("s_waitcnt vmcnt(4)" ::: "memory");  // V(it) done; K(it+1) still in flight
    } else {
      asm volatile("s_waitcnt vmcnt(0)" ::: "memory");
    }
    __builtin_amdgcn_s_barrier();
    __builtin_amdgcn_sched_barrier(0);

    __builtin_amdgcn_s_setprio(1);
#pragma unroll
    for (int nf = 0; nf < 4; ++nf) {
      int e = eh * 128 + nf * 32 + r31;
      const char* vrow = VB + ((e << 6) ^ ((e & 4) << 4));   // bit6 row-pair swap
      int swzv = (e & 3) << 4;
#pragma unroll
      for (int c = 0; c < 2; ++c) {
        f16x8 v = *reinterpret_cast<const f16x8*>(vrow + ((c * 32 + hi * 16) ^ swzv));
        o4[nf] = __builtin_amdgcn_mfma_f32_32x32x16_f16(pa[c].v, v, o4[nf], 0, 0, 0);
      }
    }
    __builtin_amdgcn_s_setprio(0);
  }

  // ---- epilogue: /(16*l) * inp, direct store (waves own disjoint 32q x 128e) ----
  float linv = 1.0f / (16.0f * lrow);
  float lr[16];
#pragma unroll
  for (int m = 0; m < 16; ++m) lr[m] = __shfl(linv, (m & 3) + 8 * (m >> 2) + 4 * hi);
  const long ob = (bN + qt * 64 + qg * 32) << 8;
#pragma unroll
  for (int nf = 0; nf < 4; ++nf)
#pragma unroll
    for (int m = 0; m < 16; ++m) {
      int qr = (m & 3) + 8 * (m >> 2) + 4 * hi;
      long off = ob + ((long)qr << 8) + eh * 128 + nf * 32 + r31;
      out[off] = o4[nf][m] * lr[m] * inp[off];
    }
}

// ---------------- host ----------------
// ws layout (bytes):
//   [0,   16M)  x1h f16
//   [16M, 32M)  x1T f16
//   [32M, 48M)  in_hi bf16 (conv temp)
//   [48M, 64M)  in_lo bf16 (conv temp)
//   [64M, +2.3M) whT, wlT (conv temps)
extern "C" void kernel_launch(void* const* d_in, const int* in_sizes, int n_in,
                              void* d_out, int out_size, void* d_ws, size_t ws_size,
                              hipStream_t stream) {
  const float* inp   = (const float*)d_in[0];
  const float* convw = (const float*)d_in[1];
  const float* convb = (const float*)d_in[2];
  float* out = (float*)d_out;
  char* ws = (char*)d_ws;

  u16* x1h   = (u16*)(ws);                 // f16
  u16* x1T   = (u16*)(ws + 16777216L);     // f16, transposed
  u16* in_hi = (u16*)(ws + 33554432L);
  u16* in_lo = (u16*)(ws + 50331648L);
  u16* whT   = (u16*)(ws + 67108864L);
  u16* wlT   = (u16*)(ws + 67108864L + 1179648L);

  k_split<<<8192, 256, 0, stream>>>(inp, in_hi, in_lo, 2097152);
  k_wsplit<<<2304, 256, 0, stream>>>(convw, whT, wlT);
  k_conv<<<512, 256, 0, stream>>>(in_hi, in_lo, whT, wlT, convb, x1h);
  k_trans<<<2048, 256, 0, stream>>>(x1h, x1T);
  k_flash3<<<512, 256, 0, stream>>>(x1h, x1T, inp, out);
}

// Round 10
// 430.680 us; speedup vs baseline: 1.8128x; 1.0013x over previous
//
#include <hip/hip_runtime.h>
#include <hip/hip_bf16.h>

typedef __attribute__((ext_vector_type(8))) short bf16x8;   // 8 bf16 (conv)
typedef __attribute__((ext_vector_type(4))) float f32x4;
typedef __attribute__((ext_vector_type(8))) _Float16 f16x8; // MFMA f16 A/B frag
typedef __attribute__((ext_vector_type(16))) float f32x16;  // 32x32 MFMA C/D
typedef __hip_bfloat16 bf16;
typedef unsigned short u16;

#define NB 8
#define NE 256
#define NN 4096
#define SD 64

__device__ __forceinline__ u16 f2b_bits(float x) {
  bf16 h = __float2bfloat16(x);
  return *reinterpret_cast<u16*>(&h);
}
__device__ __forceinline__ f32x16 z16() {
  f32x16 v;
#pragma unroll
  for (int i = 0; i < 16; ++i) v[i] = 0.f;
  return v;
}
__device__ __forceinline__ void gload_lds16(const void* g, void* l) {
  __builtin_amdgcn_global_load_lds((const __attribute__((address_space(1))) void*)g,
                                   (__attribute__((address_space(3))) void*)l, 16, 0, 0);
}

// lane-half swap: a' = {a_lo, b_lo}, b' = {a_hi, b_hi} (T12)
#if __has_builtin(__builtin_amdgcn_permlane32_swap)
typedef int i32x2 __attribute__((ext_vector_type(2)));
__device__ __forceinline__ void plswap(int& a, int& b) {
  i32x2 r = __builtin_amdgcn_permlane32_swap(a, b, false, false);
  a = r[0]; b = r[1];
}
#else
__device__ __forceinline__ void plswap(int& a, int& b) {
  int xa = __shfl_xor(a, 32), xb = __shfl_xor(b, 32);
  int hi = (int)((threadIdx.x & 63) >> 5);
  int na = hi ? xb : a;
  int nb = hi ? b : xa;
  a = na; b = nb;
}
#endif

// ---------------- split f32 -> bf16 hi/lo (conv inputs) ----------------
__global__ __launch_bounds__(256) void k_split(const float* __restrict__ x,
                                               u16* __restrict__ hi, u16* __restrict__ lo, int n4) {
  int i = blockIdx.x * 256 + threadIdx.x;
  if (i >= n4) return;
  float4 v = reinterpret_cast<const float4*>(x)[i];
  float f[4] = {v.x, v.y, v.z, v.w};
  u16 hh[4], ll[4];
#pragma unroll
  for (int j = 0; j < 4; ++j) {
    bf16 hb = __float2bfloat16(f[j]);
    float hf = __bfloat162float(hb);
    hh[j] = *reinterpret_cast<u16*>(&hb);
    ll[j] = f2b_bits(f[j] - hf);
  }
  reinterpret_cast<ushort4*>(hi)[i] = make_ushort4(hh[0], hh[1], hh[2], hh[3]);
  reinterpret_cast<ushort4*>(lo)[i] = make_ushort4(ll[0], ll[1], ll[2], ll[3]);
}

// ------- split + transpose conv weights: w[t][ei][eo] -> whT[t][eo][ei] -------
__global__ __launch_bounds__(256) void k_wsplit(const float* __restrict__ w,
                                                u16* __restrict__ whT, u16* __restrict__ wlT) {
  int i = blockIdx.x * 256 + threadIdx.x;
  int t = i >> 16;
  int r = i & 65535;
  int ei = r >> 8, eo = r & 255;
  float x = w[i];
  bf16 hb = __float2bfloat16(x);
  float hf = __bfloat162float(hb);
  int o = (t << 16) + (eo << 8) + ei;
  whT[o] = *reinterpret_cast<u16*>(&hb);
  wlT[o] = f2b_bits(x - hf);
}

// ---------------- conv 3x3 implicit GEMM, split-bf16; epilogue -> f16 ----------------
__global__ __launch_bounds__(256) void k_conv(const u16* __restrict__ inh, const u16* __restrict__ inl,
                                              const u16* __restrict__ whT, const u16* __restrict__ wlT,
                                              const float* __restrict__ bias,
                                              u16* __restrict__ x1h) {
  __shared__ u16 Ah[128][72], Al[128][72];
  __shared__ u16 Bh[128][72], Bl[128][72];
  int b = blockIdx.x >> 6;
  int rem = blockIdx.x & 63;
  int mt = rem >> 1, et = rem & 1;
  int h0 = mt << 1;
  int tid = threadIdx.x;
  int wid = tid >> 6, lane = tid & 63;
  int wr = wid >> 1, wc = wid & 1;
  int r = lane & 15, g = lane >> 4;
  f32x4 acc[4][4];
#pragma unroll
  for (int i = 0; i < 4; ++i)
#pragma unroll
    for (int j = 0; j < 4; ++j) acc[i][j] = (f32x4){0.f, 0.f, 0.f, 0.f};
  const long ibase = (long)b * NN * NE;

#pragma unroll 1
  for (int t = 0; t < 9; ++t) {
    int dy = t / 3 - 1, dx = t % 3 - 1;
#pragma unroll 1
    for (int kc = 0; kc < 4; ++kc) {
      __syncthreads();
      for (int c = tid; c < 1024; c += 256) {
        int pix = c >> 3, c8 = c & 7;
        int ww = pix & 63, hh = h0 + (pix >> 6);
        int sh = hh + dy, sw = ww + dx;
        float4 vh = make_float4(0.f, 0.f, 0.f, 0.f), vl = vh;
        if ((unsigned)sh < 64u && (unsigned)sw < 64u) {
          long off = ibase + ((long)sh * 64 + sw) * NE + kc * 64 + c8 * 8;
          vh = *reinterpret_cast<const float4*>(inh + off);
          vl = *reinterpret_cast<const float4*>(inl + off);
        }
        *reinterpret_cast<float4*>(&Ah[pix][c8 * 8]) = vh;
        *reinterpret_cast<float4*>(&Al[pix][c8 * 8]) = vl;
      }
      for (int c = tid; c < 1024; c += 256) {
        int eo = c >> 3, c8 = c & 7;
        long off = ((long)t << 16) + (et * 128 + eo) * 256 + kc * 64 + c8 * 8;
        *reinterpret_cast<float4*>(&Bh[eo][c8 * 8]) = *reinterpret_cast<const float4*>(whT + off);
        *reinterpret_cast<float4*>(&Bl[eo][c8 * 8]) = *reinterpret_cast<const float4*>(wlT + off);
      }
      __syncthreads();
#pragma unroll
      for (int ks = 0; ks < 2; ++ks) {
        int c8 = ks * 4 + g;
        bf16x8 ah[4], al[4], bh[4], bl[4];
#pragma unroll
        for (int mi = 0; mi < 4; ++mi) {
          int row = wr * 64 + mi * 16 + r;
          ah[mi] = *reinterpret_cast<const bf16x8*>(&Ah[row][c8 * 8]);
          al[mi] = *reinterpret_cast<const bf16x8*>(&Al[row][c8 * 8]);
        }
#pragma unroll
        for (int ni = 0; ni < 4; ++ni) {
          int col = wc * 64 + ni * 16 + r;
          bh[ni] = *reinterpret_cast<const bf16x8*>(&Bh[col][c8 * 8]);
          bl[ni] = *reinterpret_cast<const bf16x8*>(&Bl[col][c8 * 8]);
        }
#pragma unroll
        for (int mi = 0; mi < 4; ++mi)
#pragma unroll
          for (int ni = 0; ni < 4; ++ni) {
            acc[mi][ni] = __builtin_amdgcn_mfma_f32_16x16x32_bf16(ah[mi], bh[ni], acc[mi][ni], 0, 0, 0);
            acc[mi][ni] = __builtin_amdgcn_mfma_f32_16x16x32_bf16(ah[mi], bl[ni], acc[mi][ni], 0, 0, 0);
            acc[mi][ni] = __builtin_amdgcn_mfma_f32_16x16x32_bf16(al[mi], bh[ni], acc[mi][ni], 0, 0, 0);
          }
      }
    }
  }
#pragma unroll
  for (int mi = 0; mi < 4; ++mi)
#pragma unroll
    for (int ni = 0; ni < 4; ++ni) {
      int eo = et * 128 + wc * 64 + ni * 16 + r;
      float bz = bias[eo];
#pragma unroll
      for (int i = 0; i < 4; ++i) {
        int pix = mt * 128 + wr * 64 + mi * 16 + g * 4 + i;
        float v = acc[mi][ni][i] + bz;
        long o = ibase + (long)pix * NE + eo;
        x1h[o] = __builtin_bit_cast(u16, (_Float16)v);
      }
    }
}

// ---------------- transpose x1h[b][m][e] -> x1T[b][e][m] ----------------
__global__ __launch_bounds__(256) void k_trans(const u16* __restrict__ x1h, u16* __restrict__ x1T) {
  __shared__ u16 T[64][72];
  int bid = blockIdx.x;
  int b = bid >> 8, rem = bid & 255;
  int mt = rem >> 2, et = rem & 3;
  int tid = threadIdx.x;
  for (int c = tid; c < 512; c += 256) {
    int rr = c >> 3, c8 = c & 7;
    *reinterpret_cast<float4*>(&T[rr][c8 * 8]) =
        *reinterpret_cast<const float4*>(x1h + ((long)b * NN + mt * 64 + rr) * NE + et * 64 + c8 * 8);
  }
  __syncthreads();
  for (int c = tid; c < 512; c += 256) {
    int er = c >> 3, m8 = c & 7;
    union { u16 u[8]; float4 v; } p;
#pragma unroll
    for (int j = 0; j < 8; ++j) p.u[j] = T[m8 * 8 + j][er];
    *reinterpret_cast<float4*>(x1T + ((long)b * NE + et * 64 + er) * NN + mt * 64 + m8 * 8) = p.v;
  }
}

// ---------------- fused flash attention, f16, 32x32 MFMA, e-split, 1-barrier ----------------
// grid 512 = 8b x 64 q-tiles of 64 rows (phys&7 = batch = XCD). block 256 = 4 waves:
// eh = wid&1 (output-dim half), qg = wid>>1. Wave: 32 q-rows x 128 dims; o[4]=64 regs
// -> 2 blocks/CU (__launch_bounds__(256,2)).
// LDS 64KB: K dbuf 2x16KB @0, V dbuf 2x16KB @32K. ONE barrier/iter:
//   vmcnt(0) [K,V(it) landed]; barrier [PV(it-1) reads done]; issue stage K,V(it+1)
//   into other buf (loads hide under whole iter, T14); QK(it); softmax; PV(it) - no wait.
// QK chain split (stA/stB) for 2x MFMA ILP.
// K swz: byte ^ ((r&15)<<4) in 512B rows. V swz: bit6 row-pair swap + ((e&3)<<4).
__device__ __forceinline__ void stage_K(const u16* __restrict__ x1h16, char* dstb,
                                        long bN, int kv0, int wid, int lane) {
#pragma unroll
  for (int i = 0; i < 4; ++i) {
    int c = wid * 4 + i;                        // 16 chunks of 1KB (2 rows each)
    int r = c * 2 + (lane >> 5);
    int colb = ((lane & 31) << 4) ^ ((r & 15) << 4);
    const u16* src = x1h16 + ((bN + kv0 + r) << 8) + (colb >> 1);
    gload_lds16(src, dstb + c * 1024);          // HW adds lane*16
  }
}
__device__ __forceinline__ void stage_V(const u16* __restrict__ x1T, char* dstb,
                                        long vtb, int kv0, int wid, int lane) {
#pragma unroll
  for (int i = 0; i < 4; ++i) {
    int c = wid * 4 + i;                        // 16 chunks of 1KB (16 phys rows of 64B)
    int rp = c * 16 + (lane >> 2);
    int e = rp ^ ((rp >> 2) & 1);               // involutive row-pair swap
    int colb = ((lane & 3) << 4) ^ ((e & 3) << 4);
    const u16* src = x1T + vtb + ((long)e << 12) + kv0 + (colb >> 1);
    gload_lds16(src, dstb + c * 1024);
  }
}

__global__ __launch_bounds__(256, 2) void k_flash3(const u16* __restrict__ x1h16,
                                                   const u16* __restrict__ x1T,
                                                   const float* __restrict__ inp,
                                                   float* __restrict__ out) {
  __shared__ char LDS[65536];
  int phys = blockIdx.x;
  int b = phys & 7;                             // batch == XCD
  int qt = phys >> 3;                           // q-tile of 64 rows (0..63)
  int tid = threadIdx.x, wid = tid >> 6, lane = tid & 63;
  int r31 = lane & 31, hi = lane >> 5;
  int eh = wid & 1, qg = wid >> 1;
  const long bN = (long)b << 12;
  const long vtb = (long)b << 20;

  // Q (f16) in regs: B-frag of S^T=mfma(K,Q): col=lane&31=qrow, k=hi*8+j
  const long qrow = bN + qt * 64 + qg * 32 + r31;
  f16x8 qh[16];
#pragma unroll
  for (int ks = 0; ks < 16; ++ks)
    qh[ks] = *reinterpret_cast<const f16x8*>(x1h16 + (qrow << 8) + ks * 16 + hi * 8);

  f32x16 o4[4];                                 // 128 output dims (eh half) = 64 regs
#pragma unroll
  for (int nf = 0; nf < 4; ++nf) o4[nf] = z16();
  float mrow = -1.0e30f, lrow = 0.f;

  stage_K(x1h16, LDS, bN, 0, wid, lane);        // K(0) -> Kbuf0
  stage_V(x1T, LDS + 32768, vtb, 0, wid, lane); // V(0) -> Vbuf0

#pragma unroll 1
  for (int it = 0; it < 128; ++it) {
    const char* KB = LDS + (it & 1) * 16384;
    const char* VB = LDS + 32768 + (it & 1) * 16384;

    asm volatile("s_waitcnt vmcnt(0)" ::: "memory");   // own K,V(it) landed
    __builtin_amdgcn_s_barrier();                      // all waves: (it) ready, PV(it-1) done
    __builtin_amdgcn_sched_barrier(0);

    // ---- issue next stages first: whole iteration hides the HBM latency ----
    if (it < 127) {
      stage_K(x1h16, LDS + ((it + 1) & 1) * 16384, bN, (it + 1) * 32, wid, lane);
      stage_V(x1T, LDS + 32768 + ((it + 1) & 1) * 16384, vtb, (it + 1) * 32, wid, lane);
    }

    // ---- S^T = K.Q (32 kv x 32 q), two parallel chains ----
    f32x16 stA = z16(), stB = z16();
    int swzk = (r31 & 15) << 4;
    int krow = r31 << 9;
    __builtin_amdgcn_s_setprio(1);
#pragma unroll
    for (int ks = 0; ks < 8; ++ks) {
      int cbyA = ((2 * ks) * 32 + hi * 16) ^ swzk;
      int cbyB = ((2 * ks + 1) * 32 + hi * 16) ^ swzk;
      f16x8 kA = *reinterpret_cast<const f16x8*>(KB + krow + cbyA);
      f16x8 kB = *reinterpret_cast<const f16x8*>(KB + krow + cbyB);
      stA = __builtin_amdgcn_mfma_f32_32x32x16_f16(kA, qh[2 * ks], stA, 0, 0, 0);
      stB = __builtin_amdgcn_mfma_f32_32x32x16_f16(kB, qh[2 * ks + 1], stB, 0, 0, 0);
    }
    __builtin_amdgcn_s_setprio(0);
    f32x16 st;
#pragma unroll
    for (int m = 0; m < 16; ++m) st[m] = stA[m] + stB[m];

    // ---- online softmax (qrow = lane&31; kv = (m&3)+8*(m>>2)+4*hi), tree reduces ----
    float t8[8];
#pragma unroll
    for (int m = 0; m < 8; ++m) t8[m] = fmaxf(st[m], st[m + 8]);
    float t4a = fmaxf(t8[0], t8[4]), t4b = fmaxf(t8[1], t8[5]);
    float t4c = fmaxf(t8[2], t8[6]), t4d = fmaxf(t8[3], t8[7]);
    float tmax = fmaxf(fmaxf(t4a, t4b), fmaxf(t4c, t4d));
    tmax = fmaxf(tmax, __shfl_xor(tmax, 32));
    if (!__all(tmax <= mrow + 8.0f)) {          // defer-max (T13)
      float mnew = fmaxf(mrow, tmax);
      float alpha = __expf(mrow - mnew);
      lrow *= alpha;
      float ar[16];
#pragma unroll
      for (int m = 0; m < 16; ++m) ar[m] = __shfl(alpha, (m & 3) + 8 * (m >> 2) + 4 * hi);
#pragma unroll
      for (int nf = 0; nf < 4; ++nf)
#pragma unroll
        for (int m = 0; m < 16; ++m) o4[nf][m] *= ar[m];
      mrow = mnew;
    }
#pragma unroll
    for (int m = 0; m < 16; ++m) st[m] = __expf(st[m] - mrow);
    float s8[8];
#pragma unroll
    for (int m = 0; m < 8; ++m) s8[m] = st[m] + st[m + 8];
    float s4a = s8[0] + s8[4], s4b = s8[1] + s8[5], s4c = s8[2] + s8[6], s4d = s8[3] + s8[7];
    float psum = (s4a + s4b) + (s4c + s4d);
    psum += __shfl_xor(psum, 32);
    lrow += psum;

    // ---- P -> f16, re-fragment via permlane32_swap: 2 A-frags (kv chunks of 16) ----
    int Wd[8];
#pragma unroll
    for (int m = 0; m < 8; ++m) {
      unsigned l0 = __builtin_bit_cast(u16, (_Float16)st[2 * m]);
      unsigned h0 = __builtin_bit_cast(u16, (_Float16)st[2 * m + 1]);
      Wd[m] = (int)(l0 | (h0 << 16));
    }
    plswap(Wd[0], Wd[2]); plswap(Wd[1], Wd[3]);
    plswap(Wd[4], Wd[6]); plswap(Wd[5], Wd[7]);
    union PU { int w[4]; f16x8 v; };
    PU pa[2];
#pragma unroll
    for (int c = 0; c < 2; ++c) {
      pa[c].w[0] = Wd[c * 4 + 0]; pa[c].w[1] = Wd[c * 4 + 1];
      pa[c].w[2] = Wd[c * 4 + 2]; pa[c].w[3] = Wd[c * 4 + 3];
    }

    // ---- O += P.V over this wave's e-half (V(it) resident since last iter) ----
    __builtin_amdgcn_s_setprio(1);
#pragma unroll
    for (int nf = 0; nf < 4; ++nf) {
      int e = eh * 128 + nf * 32 + r31;
      const char* vrow = VB + ((e << 6) ^ ((e & 4) << 4));   // bit6 row-pair swap
      int swzv = (e & 3) << 4;
#pragma unroll
      for (int c = 0; c < 2; ++c) {
        f16x8 v = *reinterpret_cast<const f16x8*>(vrow + ((c * 32 + hi * 16) ^ swzv));
        o4[nf] = __builtin_amdgcn_mfma_f32_32x32x16_f16(pa[c].v, v, o4[nf], 0, 0, 0);
      }
    }
    __builtin_amdgcn_s_setprio(0);
  }

  // ---- epilogue: /(16*l) * inp, direct store (waves own disjoint 32q x 128e) ----
  float linv = 1.0f / (16.0f * lrow);
  float lr[16];
#pragma unroll
  for (int m = 0; m < 16; ++m) lr[m] = __shfl(linv, (m & 3) + 8 * (m >> 2) + 4 * hi);
  const long ob = (bN + qt * 64 + qg * 32) << 8;
#pragma unroll
  for (int nf = 0; nf < 4; ++nf)
#pragma unroll
    for (int m = 0; m < 16; ++m) {
      int qr = (m & 3) + 8 * (m >> 2) + 4 * hi;
      long off = ob + ((long)qr << 8) + eh * 128 + nf * 32 + r31;
      out[off] = o4[nf][m] * lr[m] * inp[off];
    }
}

// ---------------- host ----------------
// ws layout (bytes):
//   [0,   16M)  x1h f16
//   [16M, 32M)  x1T f16
//   [32M, 48M)  in_hi bf16 (conv temp)
//   [48M, 64M)  in_lo bf16 (conv temp)
//   [64M, +2.3M) whT, wlT (conv temps)
extern "C" void kernel_launch(void* const* d_in, const int* in_sizes, int n_in,
                              void* d_out, int out_size, void* d_ws, size_t ws_size,
                              hipStream_t stream) {
  const float* inp   = (const float*)d_in[0];
  const float* convw = (const float*)d_in[1];
  const float* convb = (const float*)d_in[2];
  float* out = (float*)d_out;
  char* ws = (char*)d_ws;

  u16* x1h   = (u16*)(ws);                 // f16
  u16* x1T   = (u16*)(ws + 16777216L);     // f16, transposed
  u16* in_hi = (u16*)(ws + 33554432L);
  u16* in_lo = (u16*)(ws + 50331648L);
  u16* whT   = (u16*)(ws + 67108864L);
  u16* wlT   = (u16*)(ws + 67108864L + 1179648L);

  k_split<<<8192, 256, 0, stream>>>(inp, in_hi, in_lo, 2097152);
  k_wsplit<<<2304, 256, 0, stream>>>(convw, whT, wlT);
  k_conv<<<512, 256, 0, stream>>>(in_hi, in_lo, whT, wlT, convb, x1h);
  k_trans<<<2048, 256, 0, stream>>>(x1h, x1T);
  k_flash3<<<512, 256, 0, stream>>>(x1h, x1T, inp, out);
}

// Round 11
// 367.986 us; speedup vs baseline: 2.1216x; 1.1704x over previous
//
#include <hip/hip_runtime.h>
#include <hip/hip_bf16.h>

typedef __attribute__((ext_vector_type(4))) float f32x4;
typedef __attribute__((ext_vector_type(8))) _Float16 f16x8; // MFMA f16 A/B frag
typedef __attribute__((ext_vector_type(16))) float f32x16;  // 32x32 MFMA C/D
typedef unsigned short u16;

#define NB 8
#define NE 256
#define NN 4096
#define SD 64

__device__ __forceinline__ f32x16 z16() {
  f32x16 v;
#pragma unroll
  for (int i = 0; i < 16; ++i) v[i] = 0.f;
  return v;
}
__device__ __forceinline__ void gload_lds16(const void* g, void* l) {
  __builtin_amdgcn_global_load_lds((const __attribute__((address_space(1))) void*)g,
                                   (__attribute__((address_space(3))) void*)l, 16, 0, 0);
}

// lane-half swap: a' = {a_lo, b_lo}, b' = {a_hi, b_hi} (T12)
#if __has_builtin(__builtin_amdgcn_permlane32_swap)
typedef int i32x2 __attribute__((ext_vector_type(2)));
__device__ __forceinline__ void plswap(int& a, int& b) {
  i32x2 r = __builtin_amdgcn_permlane32_swap(a, b, false, false);
  a = r[0]; b = r[1];
}
#else
__device__ __forceinline__ void plswap(int& a, int& b) {
  int xa = __shfl_xor(a, 32), xb = __shfl_xor(b, 32);
  int hi = (int)((threadIdx.x & 63) >> 5);
  int na = hi ? xb : a;
  int nb = hi ? b : xa;
  a = na; b = nb;
}
#endif

// ---------------- f32 -> f16 convert (conv input) ----------------
__global__ __launch_bounds__(256) void k_split(const float* __restrict__ x,
                                               u16* __restrict__ outF, int n4) {
  int i = blockIdx.x * 256 + threadIdx.x;
  if (i >= n4) return;
  float4 v = reinterpret_cast<const float4*>(x)[i];
  ushort4 o;
  o.x = __builtin_bit_cast(u16, (_Float16)v.x);
  o.y = __builtin_bit_cast(u16, (_Float16)v.y);
  o.z = __builtin_bit_cast(u16, (_Float16)v.z);
  o.w = __builtin_bit_cast(u16, (_Float16)v.w);
  reinterpret_cast<ushort4*>(outF)[i] = o;
}

// ------- convert + transpose conv weights: w[t][ei][eo] -> wT[t][eo][ei] (f16) -------
__global__ __launch_bounds__(256) void k_wsplit(const float* __restrict__ w,
                                                u16* __restrict__ wT) {
  int i = blockIdx.x * 256 + threadIdx.x;   // < 9*256*256
  int t = i >> 16;
  int r = i & 65535;
  int ei = r >> 8, eo = r & 255;
  int o = (t << 16) + (eo << 8) + ei;
  wT[o] = __builtin_bit_cast(u16, (_Float16)w[i]);
}

// ---------------- conv 3x3 implicit GEMM, single f16; epilogue -> f16 ----------------
// grid = 8b x 32mt x 2et; block 256 (4 waves 2x2, each 64pix x 64eo). LDS 36KB -> 3+ blocks/CU.
__global__ __launch_bounds__(256, 3) void k_conv(const u16* __restrict__ inF,
                                                 const u16* __restrict__ wT,
                                                 const float* __restrict__ bias,
                                                 u16* __restrict__ x1h) {
  __shared__ u16 Ah[128][72];
  __shared__ u16 Bh[128][72];
  int b = blockIdx.x >> 6;
  int rem = blockIdx.x & 63;
  int mt = rem >> 1, et = rem & 1;
  int h0 = mt << 1;
  int tid = threadIdx.x;
  int wid = tid >> 6, lane = tid & 63;
  int wr = wid >> 1, wc = wid & 1;
  int r = lane & 15, g = lane >> 4;
  f32x4 acc[4][4];
#pragma unroll
  for (int i = 0; i < 4; ++i)
#pragma unroll
    for (int j = 0; j < 4; ++j) acc[i][j] = (f32x4){0.f, 0.f, 0.f, 0.f};
  const long ibase = (long)b * NN * NE;

#pragma unroll 1
  for (int t = 0; t < 9; ++t) {
    int dy = t / 3 - 1, dx = t % 3 - 1;
#pragma unroll 1
    for (int kc = 0; kc < 4; ++kc) {
      __syncthreads();
      for (int c = tid; c < 1024; c += 256) {
        int pix = c >> 3, c8 = c & 7;
        int ww = pix & 63, hh = h0 + (pix >> 6);
        int sh = hh + dy, sw = ww + dx;
        float4 vh = make_float4(0.f, 0.f, 0.f, 0.f);
        if ((unsigned)sh < 64u && (unsigned)sw < 64u) {
          long off = ibase + ((long)sh * 64 + sw) * NE + kc * 64 + c8 * 8;
          vh = *reinterpret_cast<const float4*>(inF + off);
        }
        *reinterpret_cast<float4*>(&Ah[pix][c8 * 8]) = vh;
      }
      for (int c = tid; c < 1024; c += 256) {
        int eo = c >> 3, c8 = c & 7;
        long off = ((long)t << 16) + (et * 128 + eo) * 256 + kc * 64 + c8 * 8;
        *reinterpret_cast<float4*>(&Bh[eo][c8 * 8]) = *reinterpret_cast<const float4*>(wT + off);
      }
      __syncthreads();
#pragma unroll
      for (int ks = 0; ks < 2; ++ks) {
        int c8 = ks * 4 + g;
        f16x8 ah[4], bh[4];
#pragma unroll
        for (int mi = 0; mi < 4; ++mi)
          ah[mi] = *reinterpret_cast<const f16x8*>(&Ah[wr * 64 + mi * 16 + r][c8 * 8]);
#pragma unroll
        for (int ni = 0; ni < 4; ++ni)
          bh[ni] = *reinterpret_cast<const f16x8*>(&Bh[wc * 64 + ni * 16 + r][c8 * 8]);
#pragma unroll
        for (int mi = 0; mi < 4; ++mi)
#pragma unroll
          for (int ni = 0; ni < 4; ++ni)
            acc[mi][ni] = __builtin_amdgcn_mfma_f32_16x16x32_f16(ah[mi], bh[ni], acc[mi][ni], 0, 0, 0);
      }
    }
  }
#pragma unroll
  for (int mi = 0; mi < 4; ++mi)
#pragma unroll
    for (int ni = 0; ni < 4; ++ni) {
      int eo = et * 128 + wc * 64 + ni * 16 + r;
      float bz = bias[eo];
#pragma unroll
      for (int i = 0; i < 4; ++i) {
        int pix = mt * 128 + wr * 64 + mi * 16 + g * 4 + i;
        float v = acc[mi][ni][i] + bz;
        long o = ibase + (long)pix * NE + eo;
        x1h[o] = __builtin_bit_cast(u16, (_Float16)v);
      }
    }
}

// ---------------- transpose x1h[b][m][e] -> x1T[b][e][m] ----------------
__global__ __launch_bounds__(256) void k_trans(const u16* __restrict__ x1h, u16* __restrict__ x1T) {
  __shared__ u16 T[64][72];
  int bid = blockIdx.x;
  int b = bid >> 8, rem = bid & 255;
  int mt = rem >> 2, et = rem & 3;
  int tid = threadIdx.x;
  for (int c = tid; c < 512; c += 256) {
    int rr = c >> 3, c8 = c & 7;
    *reinterpret_cast<float4*>(&T[rr][c8 * 8]) =
        *reinterpret_cast<const float4*>(x1h + ((long)b * NN + mt * 64 + rr) * NE + et * 64 + c8 * 8);
  }
  __syncthreads();
  for (int c = tid; c < 512; c += 256) {
    int er = c >> 3, m8 = c & 7;
    union { u16 u[8]; float4 v; } p;
#pragma unroll
    for (int j = 0; j < 8; ++j) p.u[j] = T[m8 * 8 + j][er];
    *reinterpret_cast<float4*>(x1T + ((long)b * NE + et * 64 + er) * NN + mt * 64 + m8 * 8) = p.v;
  }
}

// ---------------- fused flash attention, f16, 32x32 MFMA, e-split, 1-barrier ----------------
// grid 512 = 8b x 64 q-tiles of 64 rows (phys&7 = batch = XCD). block 256 = 4 waves:
// eh = wid&1 (output-dim half), qg = wid>>1. Wave: 32 q-rows x 128 dims; o[4]=64 regs
// -> 2 blocks/CU (__launch_bounds__(256,2)).
// LDS 64KB: K dbuf 2x16KB @0, V dbuf 2x16KB @32K. ONE barrier/iter:
//   vmcnt(0) [K,V(it) landed]; barrier [PV(it-1) reads done]; issue stage K,V(it+1)
//   into other buf (loads hide under whole iter); QK(it); softmax; PV(it) - no wait.
// Staging source pointers precomputed per-thread, advanced by constant strides
// (K += 8192 u16 = 32 rows, V += 32 u16) - no per-iter address recompute.
// K swz: byte ^ ((r&15)<<4) in 512B rows. V swz: bit6 row-pair swap + ((e&3)<<4).
__global__ __launch_bounds__(256, 2) void k_flash3(const u16* __restrict__ x1h16,
                                                   const u16* __restrict__ x1T,
                                                   const float* __restrict__ inp,
                                                   float* __restrict__ out) {
  __shared__ char LDS[65536];
  int phys = blockIdx.x;
  int b = phys & 7;                             // batch == XCD
  int qt = phys >> 3;                           // q-tile of 64 rows (0..63)
  int tid = threadIdx.x, wid = tid >> 6, lane = tid & 63;
  int r31 = lane & 31, hi = lane >> 5;
  int eh = wid & 1, qg = wid >> 1;
  const long bN = (long)b << 12;
  const long vtb = (long)b << 20;

  // Q (f16) in regs: B-frag of S^T=mfma(K,Q): col=lane&31=qrow, k=hi*8+j
  const long qrow = bN + qt * 64 + qg * 32 + r31;
  f16x8 qh[16];
#pragma unroll
  for (int ks = 0; ks < 16; ++ks)
    qh[ks] = *reinterpret_cast<const f16x8*>(x1h16 + (qrow << 8) + ks * 16 + hi * 8);

  f32x16 o4[4];                                 // 128 output dims (eh half) = 64 regs
#pragma unroll
  for (int nf = 0; nf < 4; ++nf) o4[nf] = z16();
  float mrow = -1.0e30f, lrow = 0.f;

  // ---- precompute staging source pointers (kv0 = 0) and LDS chunk offsets ----
  const u16* kS[4];
  const u16* vS[4];
  int off[4];
#pragma unroll
  for (int i = 0; i < 4; ++i) {
    int c = wid * 4 + i;
    off[i] = c << 10;
    int kr = c * 2 + (lane >> 5);
    int kcolb = ((lane & 31) << 4) ^ ((kr & 15) << 4);
    kS[i] = x1h16 + ((bN + kr) << 8) + (kcolb >> 1);
    int rp = c * 16 + (lane >> 2);
    int e = rp ^ ((rp >> 2) & 1);               // involutive row-pair swap
    int vcolb = ((lane & 3) << 4) ^ ((e & 3) << 4);
    vS[i] = x1T + vtb + ((long)e << 12) + (vcolb >> 1);
  }

  // ---- prologue: stage K,V(0) -> buf0; pointers advance to it=1 ----
#pragma unroll
  for (int i = 0; i < 4; ++i) { gload_lds16(kS[i], LDS + off[i]); kS[i] += 8192; }
#pragma unroll
  for (int i = 0; i < 4; ++i) { gload_lds16(vS[i], LDS + 32768 + off[i]); vS[i] += 32; }

#pragma unroll 1
  for (int it = 0; it < 128; ++it) {
    const char* KB = LDS + (it & 1) * 16384;
    const char* VB = LDS + 32768 + (it & 1) * 16384;

    asm volatile("s_waitcnt vmcnt(0)" ::: "memory");   // K,V(it) landed
    __builtin_amdgcn_s_barrier();                      // all waves: (it) ready, PV(it-1) done
    __builtin_amdgcn_sched_barrier(0);

    // ---- issue next stages first: whole iteration hides the latency ----
    if (it < 127) {
      char* KD = LDS + ((it + 1) & 1) * 16384;
      char* VD = LDS + 32768 + ((it + 1) & 1) * 16384;
#pragma unroll
      for (int i = 0; i < 4; ++i) { gload_lds16(kS[i], KD + off[i]); kS[i] += 8192; }
#pragma unroll
      for (int i = 0; i < 4; ++i) { gload_lds16(vS[i], VD + off[i]); vS[i] += 32; }
    }

    // ---- S^T = K.Q (32 kv x 32 q), two parallel chains ----
    f32x16 stA = z16(), stB = z16();
    int swzk = (r31 & 15) << 4;
    int krow = r31 << 9;
    __builtin_amdgcn_s_setprio(1);
#pragma unroll
    for (int ks = 0; ks < 8; ++ks) {
      int cbyA = ((2 * ks) * 32 + hi * 16) ^ swzk;
      int cbyB = ((2 * ks + 1) * 32 + hi * 16) ^ swzk;
      f16x8 kA = *reinterpret_cast<const f16x8*>(KB + krow + cbyA);
      f16x8 kB = *reinterpret_cast<const f16x8*>(KB + krow + cbyB);
      stA = __builtin_amdgcn_mfma_f32_32x32x16_f16(kA, qh[2 * ks], stA, 0, 0, 0);
      stB = __builtin_amdgcn_mfma_f32_32x32x16_f16(kB, qh[2 * ks + 1], stB, 0, 0, 0);
    }
    __builtin_amdgcn_s_setprio(0);
    f32x16 st;
#pragma unroll
    for (int m = 0; m < 16; ++m) st[m] = stA[m] + stB[m];

    // ---- online softmax (qrow = lane&31; kv = (m&3)+8*(m>>2)+4*hi), tree reduces ----
    float t8[8];
#pragma unroll
    for (int m = 0; m < 8; ++m) t8[m] = fmaxf(st[m], st[m + 8]);
    float t4a = fmaxf(t8[0], t8[4]), t4b = fmaxf(t8[1], t8[5]);
    float t4c = fmaxf(t8[2], t8[6]), t4d = fmaxf(t8[3], t8[7]);
    float tmax = fmaxf(fmaxf(t4a, t4b), fmaxf(t4c, t4d));
    tmax = fmaxf(tmax, __shfl_xor(tmax, 32));
    if (!__all(tmax <= mrow + 8.0f)) {          // defer-max (T13)
      float mnew = fmaxf(mrow, tmax);
      float alpha = __expf(mrow - mnew);
      lrow *= alpha;
      float ar[16];
#pragma unroll
      for (int m = 0; m < 16; ++m) ar[m] = __shfl(alpha, (m & 3) + 8 * (m >> 2) + 4 * hi);
#pragma unroll
      for (int nf = 0; nf < 4; ++nf)
#pragma unroll
        for (int m = 0; m < 16; ++m) o4[nf][m] *= ar[m];
      mrow = mnew;
    }
#pragma unroll
    for (int m = 0; m < 16; ++m) st[m] = __expf(st[m] - mrow);
    float s8[8];
#pragma unroll
    for (int m = 0; m < 8; ++m) s8[m] = st[m] + st[m + 8];
    float s4a = s8[0] + s8[4], s4b = s8[1] + s8[5], s4c = s8[2] + s8[6], s4d = s8[3] + s8[7];
    float psum = (s4a + s4b) + (s4c + s4d);
    psum += __shfl_xor(psum, 32);
    lrow += psum;

    // ---- P -> f16, re-fragment via permlane32_swap: 2 A-frags (kv chunks of 16) ----
    int Wd[8];
#pragma unroll
    for (int m = 0; m < 8; ++m) {
      unsigned l0 = __builtin_bit_cast(u16, (_Float16)st[2 * m]);
      unsigned h0 = __builtin_bit_cast(u16, (_Float16)st[2 * m + 1]);
      Wd[m] = (int)(l0 | (h0 << 16));
    }
    plswap(Wd[0], Wd[2]); plswap(Wd[1], Wd[3]);
    plswap(Wd[4], Wd[6]); plswap(Wd[5], Wd[7]);
    union PU { int w[4]; f16x8 v; };
    PU pa[2];
#pragma unroll
    for (int c = 0; c < 2; ++c) {
      pa[c].w[0] = Wd[c * 4 + 0]; pa[c].w[1] = Wd[c * 4 + 1];
      pa[c].w[2] = Wd[c * 4 + 2]; pa[c].w[3] = Wd[c * 4 + 3];
    }

    // ---- O += P.V over this wave's e-half (V(it) resident) ----
    __builtin_amdgcn_s_setprio(1);
#pragma unroll
    for (int nf = 0; nf < 4; ++nf) {
      int e = eh * 128 + nf * 32 + r31;
      const char* vrow = VB + ((e << 6) ^ ((e & 4) << 4));   // bit6 row-pair swap
      int swzv = (e & 3) << 4;
#pragma unroll
      for (int c = 0; c < 2; ++c) {
        f16x8 v = *reinterpret_cast<const f16x8*>(vrow + ((c * 32 + hi * 16) ^ swzv));
        o4[nf] = __builtin_amdgcn_mfma_f32_32x32x16_f16(pa[c].v, v, o4[nf], 0, 0, 0);
      }
    }
    __builtin_amdgcn_s_setprio(0);
  }

  // ---- epilogue: /(16*l) * inp, direct store (waves own disjoint 32q x 128e) ----
  float linv = 1.0f / (16.0f * lrow);
  float lr[16];
#pragma unroll
  for (int m = 0; m < 16; ++m) lr[m] = __shfl(linv, (m & 3) + 8 * (m >> 2) + 4 * hi);
  const long ob = (bN + qt * 64 + qg * 32) << 8;
#pragma unroll
  for (int nf = 0; nf < 4; ++nf)
#pragma unroll
    for (int m = 0; m < 16; ++m) {
      int qr = (m & 3) + 8 * (m >> 2) + 4 * hi;
      long off2 = ob + ((long)qr << 8) + eh * 128 + nf * 32 + r31;
      out[off2] = o4[nf][m] * lr[m] * inp[off2];
    }
}

// ---------------- host ----------------
// ws layout (bytes):
//   [0,   16M)  x1h f16
//   [16M, 32M)  x1T f16
//   [32M, 48M)  inF f16 (conv temp)
//   [48M, +1.2M) wT f16 (conv temp)
extern "C" void kernel_launch(void* const* d_in, const int* in_sizes, int n_in,
                              void* d_out, int out_size, void* d_ws, size_t ws_size,
                              hipStream_t stream) {
  const float* inp   = (const float*)d_in[0];
  const float* convw = (const float*)d_in[1];
  const float* convb = (const float*)d_in[2];
  float* out = (float*)d_out;
  char* ws = (char*)d_ws;

  u16* x1h = (u16*)(ws);                   // f16
  u16* x1T = (u16*)(ws + 16777216L);       // f16, transposed
  u16* inF = (u16*)(ws + 33554432L);       // f16 conv input
  u16* wT  = (u16*)(ws + 50331648L);       // f16 transposed weights

  k_split<<<8192, 256, 0, stream>>>(inp, inF, 2097152);
  k_wsplit<<<2304, 256, 0, stream>>>(convw, wT);
  k_conv<<<512, 256, 0, stream>>>(inF, wT, convb, x1h);
  k_trans<<<2048, 256, 0, stream>>>(x1h, x1T);
  k_flash3<<<512, 256, 0, stream>>>(x1h, x1T, inp, out);
}